// Round 1
// baseline (587.770 us; speedup 1.0000x reference)
//
#include <hip/hip_runtime.h>

#define NN   4096
#define FIN  3000
#define MAXN 128
#define KB   48
#define FSTR 52
#define KSPLIT 10
#define KCH  300

typedef unsigned short u16;
typedef __bf16 bf16x8 __attribute__((ext_vector_type(8)));
typedef float f32x16 __attribute__((ext_vector_type(16)));

__device__ __forceinline__ float bf2f(u16 u) { union { unsigned int i; float f; } v; v.i = ((unsigned int)u) << 16; return v.f; }
__device__ __forceinline__ u16 f2bf(float f) {
    union { float f; unsigned int i; } v; v.f = f;
    return (u16)((v.i + 0x7FFFu + ((v.i >> 16) & 1u)) >> 16);
}
__device__ __forceinline__ bf16x8 bzero8() {
    union { unsigned long long q[2]; bf16x8 v; } u; u.q[0] = 0ull; u.q[1] = 0ull; return u.v;
}
__device__ __forceinline__ f32x16 fzero16() {
    f32x16 v;
    #pragma unroll
    for (int i = 0; i < 16; i++) v[i] = 0.f;
    return v;
}

// ---- dtype detector: bf16 N(0,1) u16s have exponent ~127; f32-as-u16 halves are random.
__global__ __launch_bounds__(1024) void k_detect(const u16* __restrict__ feat, int* __restrict__ flag)
{
    __shared__ int tot;
    if (threadIdx.x == 0) tot = 0;
    __syncthreads();
    int ins = 0;
    for (int i = threadIdx.x; i < 16384; i += 1024) {
        u16 u = feat[i];
        int e = (u >> 7) & 0xFF;
        if (u != 0 && (e < 90 || e > 160)) ins++;
    }
    atomicAdd(&tot, ins);
    __syncthreads();
    if (threadIdx.x == 0) *flag = (tot > 1024) ? 1 : 0;   // 1 = inputs are f32
}

// ---- convert 16 weight tensors -> f32 arena (blockIdx.y = segment) ----
__global__ __launch_bounds__(256) void k_convw(const int* __restrict__ flag,
    const void* s0, const void* s1, const void* s2, const void* s3,
    const void* s4, const void* s5, const void* s6, const void* s7,
    const void* s8, const void* s9, const void* s10, const void* s11,
    const void* s12, const void* s13, const void* s14, const void* s15,
    float* __restrict__ dst)
{
    const void* srcs[16] = {s0,s1,s2,s3,s4,s5,s6,s7,s8,s9,s10,s11,s12,s13,s14,s15};
    const int offs[16] = {0,192000,196096,196160,196224,212608,212864,245632,245760,253952,254016,262208,262336,270528,270592,274688};
    const int ns[16]   = {192000,4096,64,64,16384,256,32768,128,8192,64,8192,128,8192,64,4096,1};
    int seg = blockIdx.y;
    int i = blockIdx.x * 256 + threadIdx.x;
    if (i >= ns[seg]) return;
    float v = (*flag) ? ((const float*)srcs[seg])[i] : bf2f(((const u16*)srcs[seg])[i]);
    dst[offs[seg] + i] = v;
}

// ---- convert weight2 -> f32 in d_ws (survives the arena clobber) ----
__global__ __launch_bounds__(256) void k_convw2(const int* __restrict__ flag,
    const void* __restrict__ src, float* __restrict__ dst)
{
    int i = blockIdx.x * 256 + threadIdx.x;
    if (i >= 192000) return;
    dst[i] = (*flag) ? ((const float*)src)[i] : bf2f(((const u16*)src)[i]);
}

// ---- build Bt = W1^T as bf16 [64][3008], zero-padded in k (for the MFMA path) ----
__global__ __launch_bounds__(256) void k_convw1t(const int* __restrict__ flag,
    const void* __restrict__ w1src, u16* __restrict__ Bt)
{
    int i = blockIdx.x * 256 + threadIdx.x;      // over 64*3008
    if (i >= 64 * 3008) return;
    int c = i / 3008, k = i - c * 3008;
    float v = 0.f;
    if (k < 3000)
        v = (*flag) ? ((const float*)w1src)[(size_t)k * 64 + c]
                    : bf2f(((const u16*)w1src)[(size_t)k * 64 + c]);
    Bt[(size_t)c * 3008 + k] = f2bf(v);
}

// ---- ordered CSR build (prefix-scan, deterministic, sorted) for adj / graph_neigh ----
__global__ __launch_bounds__(256) void k_build_csr(const int* __restrict__ flag,
    const void* __restrict__ Av, const void* __restrict__ Gv,
    int* __restrict__ aCnt, int* __restrict__ aIdx,
    int* __restrict__ gCnt, int* __restrict__ gIdx)
{
    bool isf = (*flag != 0);
    const void* M = blockIdx.y ? Gv : Av;
    int* cnt = blockIdx.y ? gCnt : aCnt;
    int* idx = blockIdx.y ? gIdx : aIdx;
    int row = blockIdx.x, t = threadIdx.x;
    int c0 = t * 16;
    unsigned int mask = 0; int my = 0;
    if (isf) {
        const float* r = (const float*)M + (size_t)row * NN + c0;
        #pragma unroll
        for (int j = 0; j < 16; j++) if (r[j] != 0.f) { mask |= 1u << j; my++; }
    } else {
        const u16* r = (const u16*)M + (size_t)row * NN + c0;
        #pragma unroll
        for (int j = 0; j < 16; j++) if (r[j] != 0) { mask |= 1u << j; my++; }
    }
    __shared__ int sc[256];
    sc[t] = my;
    __syncthreads();
    for (int d = 1; d < 256; d <<= 1) {
        int v = (t >= d) ? sc[t - d] : 0;
        __syncthreads();
        sc[t] += v;
        __syncthreads();
    }
    int pos = sc[t] - my;
    for (int j = 0; j < 16; j++) {
        if (mask & (1u << j)) {
            if (pos < MAXN) idx[(size_t)row * MAXN + pos] = c0 + j;
            pos++;
        }
    }
    if (t == 0) { int total = sc[255]; cnt[row] = (total < MAXN) ? total : MAXN; }
}

// ---- f32 fallback: X += feat @ weight1, split-K atomics (only runs when flag==1) ----
__global__ __launch_bounds__(128) void k_featgemm(const int* __restrict__ flag,
    const void* __restrict__ F0v, const void* __restrict__ F1v,
    const float* __restrict__ W1f, float* __restrict__ X0, float* __restrict__ X1)
{
    bool isf = (*flag != 0);
    if (!isf) return;                      // bf16 mode: handled by k_featgemm_mfma
    const void* Fv = blockIdx.z ? F1v : F0v;
    float* X = blockIdx.z ? X1 : X0;
    int r0 = blockIdx.x * 32;
    int kbeg = blockIdx.y * KCH;
    int kend = kbeg + KCH;
    int tid = threadIdx.x;
    int cg = tid & 15, rg = tid >> 4;
    int c0 = cg * 4, rr = rg * 4;
    __shared__ float Wl[KB * 64];
    __shared__ float Fl[32 * FSTR];
    float acc[4][4] = {};
    for (int k0 = kbeg; k0 < kend; k0 += KB) {
        int rem = kend - k0;
        int nk = rem < KB ? rem : KB;
        __syncthreads();
        {
            const float4* g = (const float4*)(W1f + (size_t)k0 * 64);
            int nf4 = nk * 16;
            #pragma unroll
            for (int j = 0; j < 6; j++) {
                int i = tid + 128 * j;
                float4 v = {0.f, 0.f, 0.f, 0.f};
                if (i < nf4) v = g[i];
                ((float4*)Wl)[i] = v;
            }
        }
        {
            const float* F = (const float*)Fv;
            #pragma unroll
            for (int j = 0; j < 3; j++) {
                int i = tid + 128 * j;
                int row = i / 12, c4 = i % 12;
                int kk = c4 * 4;
                float4 v = {0.f, 0.f, 0.f, 0.f};
                if (kk < nk) v = *(const float4*)(F + (size_t)(r0 + row) * FIN + k0 + kk);
                *(float4*)(Fl + row * FSTR + kk) = v;
            }
        }
        __syncthreads();
        #pragma unroll
        for (int q = 0; q < KB; q += 4) {
            float4 w0 = *(float4*)(Wl + (q + 0) * 64 + c0);
            float4 w1 = *(float4*)(Wl + (q + 1) * 64 + c0);
            float4 w2 = *(float4*)(Wl + (q + 2) * 64 + c0);
            float4 w3 = *(float4*)(Wl + (q + 3) * 64 + c0);
            #pragma unroll
            for (int i = 0; i < 4; i++) {
                float4 f = *(float4*)(Fl + (rr + i) * FSTR + q);
                acc[i][0] += f.x * w0.x + f.y * w1.x + f.z * w2.x + f.w * w3.x;
                acc[i][1] += f.x * w0.y + f.y * w1.y + f.z * w2.y + f.w * w3.y;
                acc[i][2] += f.x * w0.z + f.y * w1.z + f.z * w2.z + f.w * w3.z;
                acc[i][3] += f.x * w0.w + f.y * w1.w + f.z * w2.w + f.w * w3.w;
            }
        }
    }
    #pragma unroll
    for (int i = 0; i < 4; i++) {
        float* xp = X + (size_t)(r0 + rr + i) * 64 + c0;
        atomicAdd(xp + 0, acc[i][0]);
        atomicAdd(xp + 1, acc[i][1]);
        atomicAdd(xp + 2, acc[i][2]);
        atomicAdd(xp + 3, acc[i][3]);
    }
}

// ---- bf16 MFMA path: X = feat @ weight1 via v_mfma_f32_32x32x16_bf16 ----
// Grid (128, 2): 32-row tile per block, 8 waves = 8 K-eighths, LDS reduce, plain store.
// A frag: lane row=l&31, k=(l>>5)*8+j (contiguous 16B load from feat row).
// B frag: lane col=l&31, k=(l>>5)*8+j (contiguous 16B load from Bt row = W1 column).
// D: col=l&31, row=(reg&3)+8*(reg>>2)+4*(l>>5).
__global__ __launch_bounds__(512) void k_featgemm_mfma(const int* __restrict__ flag,
    const void* __restrict__ F0v, const void* __restrict__ F1v,
    const u16* __restrict__ Bt, float* __restrict__ X0, float* __restrict__ X1)
{
    if (*flag) return;                     // f32 mode: handled by k_featgemm
    const u16* F = (const u16*)(blockIdx.y ? F1v : F0v);
    float* X = blockIdx.y ? X1 : X0;
    int r0 = blockIdx.x * 32;
    int tid = threadIdx.x;
    int w  = tid >> 6;                     // wave id = K-eighth
    int l  = tid & 63;
    int lr = l & 31;                       // A row / B col / D col
    int kg = l >> 5;                       // k-group (0..1), 8 elems each
    const u16* arow = F  + (size_t)(r0 + lr) * FIN + kg * 8;
    const u16* b0p  = Bt + (size_t)lr * 3008 + kg * 8;
    const u16* b1p  = Bt + (size_t)(lr + 32) * 3008 + kg * 8;
    f32x16 acc0 = fzero16(), acc1 = fzero16();
    // 188 K-steps of 16 (187 full + tail covering k 2992..2999; kg==1 of step 187 zeroed)
    #pragma unroll 4
    for (int s = w; s < 188; s += 8) {
        int kk = s * 16;
        bf16x8 a;
        if (kk + kg * 8 < FIN) a = *(const bf16x8*)(arow + kk);
        else                   a = bzero8();
        bf16x8 b0 = *(const bf16x8*)(b0p + kk);   // Bt zero-padded to 3008
        bf16x8 b1 = *(const bf16x8*)(b1p + kk);
        acc0 = __builtin_amdgcn_mfma_f32_32x32x16_bf16(a, b0, acc0, 0, 0, 0);
        acc1 = __builtin_amdgcn_mfma_f32_32x32x16_bf16(a, b1, acc1, 0, 0, 0);
    }
    __shared__ float red[8][2048];         // 64 KB: per-wave 32x64 partials
    float* rp = red[w];
    #pragma unroll
    for (int reg = 0; reg < 16; reg++) {
        int row = (reg & 3) + 8 * (reg >> 2) + 4 * kg;
        rp[row * 64 + lr] = acc0[reg];
    }
    #pragma unroll
    for (int reg = 0; reg < 16; reg++) {
        int row = (reg & 3) + 8 * (reg >> 2) + 4 * kg;
        rp[row * 64 + 32 + lr] = acc1[reg];
    }
    __syncthreads();
    for (int i = tid; i < 2048; i += 512) {
        float s0 = 0.f;
        #pragma unroll
        for (int j = 0; j < 8; j++) s0 += red[j][i];
        X[(size_t)r0 * 64 + i] = s0;
    }
}

// ---- Wh = X @ att_W; s = Wh@a_src; d = Wh@a_dst (all-f32) ----
__global__ __launch_bounds__(64) void k_whsd(
    const float* __restrict__ X1, const float* __restrict__ X2,
    const float* __restrict__ AW, const float* __restrict__ asrc, const float* __restrict__ adst,
    float* __restrict__ Wh1, float* __restrict__ Wh2,
    float* __restrict__ s1, float* __restrict__ s2,
    float* __restrict__ d1, float* __restrict__ d2)
{
    const float* X = blockIdx.y ? X2 : X1;
    float* Wh = blockIdx.y ? Wh2 : Wh1;
    float* sv = blockIdx.y ? s2 : s1;
    float* dv = blockIdx.y ? d2 : d1;
    int row = blockIdx.x, c = threadIdx.x;
    __shared__ float x[64];
    x[c] = X[(size_t)row * 64 + c];
    __syncthreads();
    float acc = 0.f;
    #pragma unroll 16
    for (int k = 0; k < 64; k++) acc += x[k] * AW[k * 64 + c];
    Wh[(size_t)row * 64 + c] = acc;
    float vs = acc * asrc[c];
    float vd = acc * adst[c];
    #pragma unroll
    for (int off = 32; off > 0; off >>= 1) { vs += __shfl_down(vs, off); vd += __shfl_down(vd, off); }
    if (c == 0) { sv[row] = vs; dv[row] = vd; }
}

// ---- masked softmax (rank-1 scores) + P @ Wh over CSR neighbors ----
__global__ __launch_bounds__(128) void k_attn(
    const int* __restrict__ cnt, const int* __restrict__ idx,
    const float* __restrict__ s1, const float* __restrict__ s2,
    const float* __restrict__ d1, const float* __restrict__ d2,
    const float* __restrict__ Wh1, const float* __restrict__ Wh2,
    float* __restrict__ A1, float* __restrict__ A2)
{
    const float* sp = blockIdx.y ? s2 : s1;
    const float* dp = blockIdx.y ? d2 : d1;
    const float* Wh = blockIdx.y ? Wh2 : Wh1;
    float* A = blockIdx.y ? A2 : A1;
    int row = blockIdx.x, tid = threadIdx.x;
    int n = cnt[row];
    __shared__ int js[MAXN];
    __shared__ float ps[MAXN];
    __shared__ float red2[2];
    __shared__ float ared[2][64];
    for (int k = tid; k < n; k += 128) js[k] = idx[(size_t)row * MAXN + k];
    __syncthreads();
    float si = sp[row];
    float m = -3.0e38f;
    for (int k = tid; k < n; k += 128) {
        float e = si + dp[js[k]];
        e = e > 0.f ? e : 0.2f * e;   // LeakyReLU(0.2)
        ps[k] = e;
        m = fmaxf(m, e);
    }
    #pragma unroll
    for (int off = 32; off > 0; off >>= 1) m = fmaxf(m, __shfl_down(m, off));
    if ((tid & 63) == 0) red2[tid >> 6] = m;
    __syncthreads();
    m = fmaxf(red2[0], red2[1]);
    __syncthreads();
    float zz = 0.f;
    for (int k = tid; k < n; k += 128) {
        float p = __expf(ps[k] - m);
        ps[k] = p;
        zz += p;
    }
    #pragma unroll
    for (int off = 32; off > 0; off >>= 1) zz += __shfl_down(zz, off);
    if ((tid & 63) == 0) red2[tid >> 6] = zz;
    __syncthreads();
    float Z = red2[0] + red2[1];
    Z = fmaxf(Z, 1e-20f);           // guard 0/0
    int f = tid & 63, half = tid >> 6;
    float acc = 0.f;
    for (int k = half; k < n; k += 2) acc += ps[k] * Wh[(size_t)js[k] * 64 + f];
    ared[half][f] = acc;
    __syncthreads();
    if (tid < 64) A[(size_t)row * 64 + f] = (ared[0][f] + ared[1][f]) / Z;
}

// ---- 3-layer MLP 64->256->128->64; 4 rows/block; writes z (f32) and hiden_emb (dual-dtype, y==0) ----
__global__ __launch_bounds__(256) void k_mlp(const int* __restrict__ flag,
    const float* __restrict__ A1, const float* __restrict__ A2,
    const float* __restrict__ W1, const float* __restrict__ b1,
    const float* __restrict__ W2, const float* __restrict__ b2,
    const float* __restrict__ W3, const float* __restrict__ b3,
    float* __restrict__ Z1, float* __restrict__ Z2, void* __restrict__ hidenv)
{
    const float* A = blockIdx.y ? A2 : A1;
    float* Z = blockIdx.y ? Z2 : Z1;
    int row0 = blockIdx.x * 4, tid = threadIdx.x;
    __shared__ float x[4][64], h1[4][256], h2[4][128];
    {
        int r = tid >> 6, c = tid & 63;
        x[r][c] = A[(size_t)(row0 + r) * 64 + c];
    }
    __syncthreads();
    {
        float a0 = b1[tid], a1v = a0, a2v = a0, a3v = a0;
        #pragma unroll 8
        for (int k = 0; k < 64; k++) {
            float w = W1[k * 256 + tid];
            a0 += x[0][k] * w; a1v += x[1][k] * w; a2v += x[2][k] * w; a3v += x[3][k] * w;
        }
        h1[0][tid] = fmaxf(a0, 0.f);  h1[1][tid] = fmaxf(a1v, 0.f);
        h1[2][tid] = fmaxf(a2v, 0.f); h1[3][tid] = fmaxf(a3v, 0.f);
    }
    __syncthreads();
    if (tid < 128) {
        float a0 = b2[tid], a1v = a0, a2v = a0, a3v = a0;
        #pragma unroll 8
        for (int k = 0; k < 256; k++) {
            float w = W2[k * 128 + tid];
            a0 += h1[0][k] * w; a1v += h1[1][k] * w; a2v += h1[2][k] * w; a3v += h1[3][k] * w;
        }
        h2[0][tid] = fmaxf(a0, 0.f);  h2[1][tid] = fmaxf(a1v, 0.f);
        h2[2][tid] = fmaxf(a2v, 0.f); h2[3][tid] = fmaxf(a3v, 0.f);
    }
    __syncthreads();
    if (tid < 64) {
        float a[4];
        a[0] = a[1] = a[2] = a[3] = b3[tid];
        #pragma unroll 8
        for (int k = 0; k < 128; k++) {
            float w = W3[k * 64 + tid];
            a[0] += h2[0][k] * w; a[1] += h2[1][k] * w; a[2] += h2[2][k] * w; a[3] += h2[3][k] * w;
        }
        bool isf = (*flag != 0);
        #pragma unroll
        for (int r = 0; r < 4; r++) {
            size_t ei = (size_t)(row0 + r) * 64 + tid;
            Z[ei] = a[r];
            if (blockIdx.y == 0) {
                if (isf) ((float*)hidenv)[ei] = a[r];
                else     ((u16*)hidenv)[ei] = f2bf(a[r]);
            }
        }
    }
}

// ---- T = adj @ z over CSR ----
__global__ __launch_bounds__(64) void k_spmm(
    const int* __restrict__ cnt, const int* __restrict__ idx,
    const float* __restrict__ Z, float* __restrict__ T)
{
    int row = blockIdx.x, f = threadIdx.x;
    int n = cnt[row];
    const int* ir = idx + (size_t)row * MAXN;
    float acc = 0.f;
    for (int k = 0; k < n; k++) acc += Z[(size_t)ir[k] * 64 + f];
    T[(size_t)row * 64 + f] = acc;
}

// ---- H = T @ weight2 -> out (dual-dtype store), 8 rows/block ----
__global__ __launch_bounds__(256) void k_hgemm(const int* __restrict__ flag,
    const float* __restrict__ T, const float* __restrict__ W2f, void* __restrict__ outv)
{
    bool isf = (*flag != 0);
    int r0 = blockIdx.x * 8, tid = threadIdx.x;
    __shared__ float tt[8][64];
    for (int i = tid; i < 512; i += 256) tt[i >> 6][i & 63] = T[(size_t)r0 * 64 + i];
    __syncthreads();
    for (int c = tid; c < FIN; c += 256) {
        float a[8] = {0,0,0,0,0,0,0,0};
        #pragma unroll 8
        for (int k = 0; k < 64; k++) {
            float w = W2f[(size_t)k * FIN + c];
            #pragma unroll
            for (int i = 0; i < 8; i++) a[i] += tt[i][k] * w;
        }
        #pragma unroll
        for (int i = 0; i < 8; i++) {
            size_t ei = 262144 + (size_t)(r0 + i) * FIN + c;
            if (isf) ((float*)outv)[ei] = a[i];
            else     ((u16*)outv)[ei] = f2bf(a[i]);
        }
    }
}

// ---- readout: mean over graph_neigh nbrs of relu(z), L2 normalize, sigmoid ----
__global__ __launch_bounds__(64) void k_readout(
    const int* __restrict__ cnt, const int* __restrict__ idx,
    const float* __restrict__ Z1, const float* __restrict__ Z2,
    float* __restrict__ G1, float* __restrict__ G2)
{
    const float* Z = blockIdx.y ? Z2 : Z1;
    float* G = blockIdx.y ? G2 : G1;
    int row = blockIdx.x, f = threadIdx.x;
    int n = cnt[row];
    const int* ir = idx + (size_t)row * MAXN;
    float acc = 0.f;
    for (int k = 0; k < n; k++) acc += fmaxf(Z[(size_t)ir[k] * 64 + f], 0.f);
    acc /= (float)(n > 0 ? n : 1);
    float sq = acc * acc;
    #pragma unroll
    for (int off = 32; off > 0; off >>= 1) sq += __shfl_down(sq, off);
    sq = __shfl(sq, 0);
    float nrm = fmaxf(sqrtf(sq), 1e-12f);
    float v = acc / nrm;
    G[(size_t)row * 64 + f] = 1.f / (1.f + __expf(-v));
}

// ---- discriminator MLP 64->128->64; 4 rows/block; on {relu(z), relu(z_a), g, g_a} ----
__global__ __launch_bounds__(128) void k_dmlp(
    const float* __restrict__ z, const float* __restrict__ za,
    const float* __restrict__ g, const float* __restrict__ ga,
    const float* __restrict__ W1, const float* __restrict__ b1,
    const float* __restrict__ W2, const float* __restrict__ b2,
    float* __restrict__ De, float* __restrict__ Dea,
    float* __restrict__ Dg, float* __restrict__ Dga)
{
    int w = blockIdx.y;
    const float* X = (w == 0) ? z : (w == 1) ? za : (w == 2) ? g : ga;
    float* O = (w == 0) ? De : (w == 1) ? Dea : (w == 2) ? Dg : Dga;
    int doRelu = (w < 2);
    int row0 = blockIdx.x * 4, tid = threadIdx.x;
    __shared__ float x[4][64], h1[4][128];
    for (int i = tid; i < 256; i += 128) {
        int r = i >> 6, c = i & 63;
        float v = X[(size_t)(row0 + r) * 64 + c];
        x[r][c] = doRelu ? fmaxf(v, 0.f) : v;
    }
    __syncthreads();
    {
        float a0 = b1[tid], a1v = a0, a2v = a0, a3v = a0;
        #pragma unroll 8
        for (int k = 0; k < 64; k++) {
            float w_ = W1[k * 128 + tid];
            a0 += x[0][k] * w_; a1v += x[1][k] * w_; a2v += x[2][k] * w_; a3v += x[3][k] * w_;
        }
        h1[0][tid] = fmaxf(a0, 0.f);  h1[1][tid] = fmaxf(a1v, 0.f);
        h1[2][tid] = fmaxf(a2v, 0.f); h1[3][tid] = fmaxf(a3v, 0.f);
    }
    __syncthreads();
    if (tid < 64) {
        float a[4];
        a[0] = a[1] = a[2] = a[3] = b2[tid];
        #pragma unroll 8
        for (int k = 0; k < 128; k++) {
            float w_ = W2[k * 64 + tid];
            a[0] += h1[0][k] * w_; a[1] += h1[1][k] * w_; a[2] += h1[2][k] * w_; a[3] += h1[3][k] * w_;
        }
        #pragma unroll
        for (int r = 0; r < 4; r++) O[(size_t)(row0 + r) * 64 + tid] = a[r];
    }
}

// ---- bilinear: out = x . (bil_W @ y) + b ; dual-dtype store ----
__global__ __launch_bounds__(64) void k_bilin(const int* __restrict__ flag,
    const float* __restrict__ De, const float* __restrict__ Dea,
    const float* __restrict__ Dg, const float* __restrict__ Dga,
    const float* __restrict__ BW, const float* __restrict__ bb, void* __restrict__ outv)
{
    int w = blockIdx.y;
    const float* X = (w == 0 || w == 3) ? De : Dea;
    const float* Y = (w <= 1) ? Dg : Dga;
    size_t bse = (w <= 1) ? (size_t)12550144 : (size_t)12558336;
    int col = (w == 0 || w == 2) ? 0 : 1;
    int row = blockIdx.x, k = threadIdx.x;
    __shared__ float x[64], y[64];
    x[k] = X[(size_t)row * 64 + k];
    y[k] = Y[(size_t)row * 64 + k];
    __syncthreads();
    float wv = 0.f;
    #pragma unroll 8
    for (int j = 0; j < 64; j++) wv += BW[k * 64 + j] * y[j];
    float v = x[k] * wv;
    #pragma unroll
    for (int off = 32; off > 0; off >>= 1) v += __shfl_down(v, off);
    if (k == 0) {
        float r = v + bb[0];
        size_t ei = bse + (size_t)row * 2 + col;
        if (*flag) ((float*)outv)[ei] = r;
        else       ((u16*)outv)[ei] = f2bf(r);
    }
}

extern "C" void kernel_launch(void* const* d_in, const int* in_sizes, int n_in,
                              void* d_out, int out_size, void* d_ws, size_t ws_size,
                              hipStream_t stream) {
    const void* feat   = d_in[0];
    const void* feat_a = d_in[1];
    const void* adj    = d_in[2];
    const void* gn     = d_in[3];
    const void* w1     = d_in[4];
    const void* w2     = d_in[5];
    const void* attW   = d_in[6];
    const void* a_src  = d_in[7];
    const void* a_dst  = d_in[8];
    const void* mW1    = d_in[9];
    const void* mb1    = d_in[10];
    const void* mW2    = d_in[11];
    const void* mb2    = d_in[12];
    const void* mW3    = d_in[13];
    const void* mb3    = d_in[14];
    const void* dW1    = d_in[15];
    const void* db1    = d_in[16];
    const void* dW2    = d_in[17];
    const void* db2    = d_in[18];
    const void* bW     = d_in[19];
    const void* bb     = d_in[20];
    (void)in_sizes; (void)n_in; (void)out_size;

    // ---- d_ws: flag + T + w2f  (~1.8 MB total; minimal footprint) ----
    char* wsb = (char*)d_ws;
    int*   flag = (int*)wsb;                        // 4 B (pad 256)
    float* T    = (float*)(wsb + 256);              // 1,048,576 B
    float* w2f  = (float*)(wsb + 256 + 1048576);    // 768,000 B
    (void)ws_size;

    // ---- scratch arena at dtype-independent byte window of d_out:
    // bytes [1,048,576 , 21,200,000) lie inside the h output region for BOTH
    // bf16 (h bytes [524288,25100288)) and f32 (h bytes [1048576,50200576)),
    // and are fully overwritten by k_hgemm at the end.
    char* sc = (char*)d_out + 1048576;
    size_t soff = 0;
    auto salloc = [&](size_t nbytes) -> void* {
        void* p = (void*)(sc + soff);
        soff += (nbytes + 255) & ~(size_t)255;
        return p;
    };
    const size_t NV = (size_t)NN * 64;
    float* wA   = (float*)salloc((size_t)274689 * 4);  // 16-segment f32 weight arena
    int*   aCnt = (int*)salloc(NN * 4);
    int*   gCnt = (int*)salloc(NN * 4);
    int*   aIdx = (int*)salloc((size_t)NN * MAXN * 4);
    int*   gIdx = (int*)salloc((size_t)NN * MAXN * 4);
    float* X1  = (float*)salloc(NV * 4);
    float* X2  = (float*)salloc(NV * 4);   // contiguous with X1 (NV*4 is 256-mult)
    float* Wh1 = (float*)salloc(NV * 4);
    float* Wh2 = (float*)salloc(NV * 4);
    float* A1  = (float*)salloc(NV * 4);
    float* A2  = (float*)salloc(NV * 4);
    float* z   = (float*)salloc(NV * 4);
    float* za  = (float*)salloc(NV * 4);
    float* g   = (float*)salloc(NV * 4);
    float* ga  = (float*)salloc(NV * 4);
    float* De  = (float*)salloc(NV * 4);
    float* Dea = (float*)salloc(NV * 4);
    float* Dg  = (float*)salloc(NV * 4);
    float* Dga = (float*)salloc(NV * 4);
    float* s1  = (float*)salloc(NN * 4);
    float* s2  = (float*)salloc(NN * 4);
    float* d1  = (float*)salloc(NN * 4);
    float* d2  = (float*)salloc(NN * 4);
    // soff ~= 20.1 MB < 20.15 MB window: fits.

    float* w1f   = wA + 0;
    float* attWf = wA + 192000;
    float* asrcf = wA + 196096;
    float* adstf = wA + 196160;
    float* mW1f  = wA + 196224;
    float* mb1f  = wA + 212608;
    float* mW2f  = wA + 212864;
    float* mb2f  = wA + 245632;
    float* mW3f  = wA + 245760;
    float* mb3f  = wA + 253952;
    float* dW1f  = wA + 254016;
    float* db1f  = wA + 262208;
    float* dW2f  = wA + 262336;
    float* db2f  = wA + 270528;
    float* bWf   = wA + 270592;
    float* bbf   = wA + 274688;

    // Bt (bf16 W1^T [64][3008], 385 KB) parks in the De slot: De is not written
    // until k_dmlp, which runs long after k_featgemm_mfma consumes Bt.
    u16* Bt = (u16*)De;

    k_detect<<<1, 1024, 0, stream>>>((const u16*)feat, flag);
    k_convw<<<dim3(750, 16), 256, 0, stream>>>(flag,
        w1, attW, a_src, a_dst, mW1, mb1, mW2, mb2, mW3, mb3,
        dW1, db1, dW2, db2, bW, bb, wA);
    k_convw2<<<750, 256, 0, stream>>>(flag, w2, w2f);
    k_convw1t<<<752, 256, 0, stream>>>(flag, w1, Bt);
    k_build_csr<<<dim3(NN, 2), 256, 0, stream>>>(flag, adj, gn, aCnt, aIdx, gCnt, gIdx);
    hipMemsetAsync(X1, 0, 2 * NV * 4, stream);   // zero X1+X2 for f32 split-K atomics
    k_featgemm<<<dim3(NN / 32, KSPLIT, 2), 128, 0, stream>>>(flag, feat, feat_a, w1f, X1, X2);
    k_featgemm_mfma<<<dim3(NN / 32, 2), 512, 0, stream>>>(flag, feat, feat_a, Bt, X1, X2);
    k_whsd<<<dim3(NN, 2), 64, 0, stream>>>(X1, X2, attWf, asrcf, adstf, Wh1, Wh2, s1, s2, d1, d2);
    k_attn<<<dim3(NN, 2), 128, 0, stream>>>(aCnt, aIdx, s1, s2, d1, d2, Wh1, Wh2, A1, A2);
    k_mlp<<<dim3(NN / 4, 2), 256, 0, stream>>>(flag, A1, A2, mW1f, mb1f, mW2f, mb2f, mW3f, mb3f, z, za, d_out);
    k_readout<<<dim3(NN, 2), 64, 0, stream>>>(gCnt, gIdx, z, za, g, ga);
    k_dmlp<<<dim3(NN / 4, 4), 128, 0, stream>>>(z, za, g, ga, dW1f, db1f, dW2f, db2f, De, Dea, Dg, Dga);
    k_bilin<<<dim3(NN, 4), 64, 0, stream>>>(flag, De, Dea, Dg, Dga, bWf, bbf, d_out);
    k_spmm<<<NN, 64, 0, stream>>>(aCnt, aIdx, z, T);
    k_hgemm<<<512, 256, 0, stream>>>(flag, T, w2f, d_out);   // overwrites arena with real h
}

// Round 2
// 493.887 us; speedup vs baseline: 1.1901x; 1.1901x over previous
//
#include <hip/hip_runtime.h>

#define NN   4096
#define FIN  3000
#define MAXN 128

typedef unsigned short u16;
typedef __bf16 bf16x8 __attribute__((ext_vector_type(8)));
typedef float f32x16 __attribute__((ext_vector_type(16)));

__device__ __forceinline__ float bf2f(u16 u) { union { unsigned int i; float f; } v; v.i = ((unsigned int)u) << 16; return v.f; }
__device__ __forceinline__ u16 f2bf(float f) {
    union { float f; unsigned int i; } v; v.f = f;
    return (u16)((v.i + 0x7FFFu + ((v.i >> 16) & 1u)) >> 16);
}
__device__ __forceinline__ bf16x8 bzero8() {
    union { unsigned long long q[2]; bf16x8 v; } u; u.q[0] = 0ull; u.q[1] = 0ull; return u.v;
}
__device__ __forceinline__ f32x16 fzero16() {
    f32x16 v;
    #pragma unroll
    for (int i = 0; i < 16; i++) v[i] = 0.f;
    return v;
}

// ---- dtype detector: bf16 N(0,1) u16s have exponent ~127; f32-as-u16 halves are random.
__global__ __launch_bounds__(1024) void k_detect(const u16* __restrict__ feat, int* __restrict__ flag)
{
    __shared__ int tot;
    if (threadIdx.x == 0) tot = 0;
    __syncthreads();
    int ins = 0;
    for (int i = threadIdx.x; i < 16384; i += 1024) {
        u16 u = feat[i];
        int e = (u >> 7) & 0xFF;
        if (u != 0 && (e < 90 || e > 160)) ins++;
    }
    atomicAdd(&tot, ins);
    __syncthreads();
    if (threadIdx.x == 0) *flag = (tot > 1024) ? 1 : 0;   // 1 = inputs are f32
}

// ---- convert 16 weight tensors -> f32 arena (blockIdx.y = segment) ----
__global__ __launch_bounds__(256) void k_convw(const int* __restrict__ flag,
    const void* s0, const void* s1, const void* s2, const void* s3,
    const void* s4, const void* s5, const void* s6, const void* s7,
    const void* s8, const void* s9, const void* s10, const void* s11,
    const void* s12, const void* s13, const void* s14, const void* s15,
    float* __restrict__ dst)
{
    const void* srcs[16] = {s0,s1,s2,s3,s4,s5,s6,s7,s8,s9,s10,s11,s12,s13,s14,s15};
    const int offs[16] = {0,192000,196096,196160,196224,212608,212864,245632,245760,253952,254016,262208,262336,270528,270592,274688};
    const int ns[16]   = {192000,4096,64,64,16384,256,32768,128,8192,64,8192,128,8192,64,4096,1};
    int seg = blockIdx.y;
    int i = blockIdx.x * 256 + threadIdx.x;
    if (i >= ns[seg]) return;
    float v = (*flag) ? ((const float*)srcs[seg])[i] : bf2f(((const u16*)srcs[seg])[i]);
    dst[offs[seg] + i] = v;
}

// ---- convert weight2 -> f32 in d_ws (survives the arena clobber) ----
__global__ __launch_bounds__(256) void k_convw2(const int* __restrict__ flag,
    const void* __restrict__ src, float* __restrict__ dst)
{
    int i = blockIdx.x * 256 + threadIdx.x;
    if (i >= 192000) return;
    dst[i] = (*flag) ? ((const float*)src)[i] : bf2f(((const u16*)src)[i]);
}

// ---- build BtH/BtL = split-bf16 W1^T [64][3008], zero-padded in k ----
// v = hi + lo + O(2^-18 * v): hi = bf16(v), lo = bf16(v - hi) (exact residual).
__global__ __launch_bounds__(256) void k_convw1t(const int* __restrict__ flag,
    const void* __restrict__ w1src, u16* __restrict__ BtH, u16* __restrict__ BtL)
{
    int i = blockIdx.x * 256 + threadIdx.x;      // over 64*3008
    if (i >= 64 * 3008) return;
    int c = i / 3008, k = i - c * 3008;
    float v = 0.f;
    if (k < 3000)
        v = (*flag) ? ((const float*)w1src)[(size_t)k * 64 + c]
                    : bf2f(((const u16*)w1src)[(size_t)k * 64 + c]);
    u16 h = f2bf(v);
    float r = v - bf2f(h);                       // exact in f32
    BtH[(size_t)c * 3008 + k] = h;
    BtL[(size_t)c * 3008 + k] = f2bf(r);
}

// ---- ordered CSR build (prefix-scan, deterministic, sorted) for adj / graph_neigh ----
__global__ __launch_bounds__(256) void k_build_csr(const int* __restrict__ flag,
    const void* __restrict__ Av, const void* __restrict__ Gv,
    int* __restrict__ aCnt, int* __restrict__ aIdx,
    int* __restrict__ gCnt, int* __restrict__ gIdx)
{
    bool isf = (*flag != 0);
    const void* M = blockIdx.y ? Gv : Av;
    int* cnt = blockIdx.y ? gCnt : aCnt;
    int* idx = blockIdx.y ? gIdx : aIdx;
    int row = blockIdx.x, t = threadIdx.x;
    int c0 = t * 16;
    unsigned int mask = 0; int my = 0;
    if (isf) {
        const float* r = (const float*)M + (size_t)row * NN + c0;
        #pragma unroll
        for (int j = 0; j < 16; j++) if (r[j] != 0.f) { mask |= 1u << j; my++; }
    } else {
        const u16* r = (const u16*)M + (size_t)row * NN + c0;
        #pragma unroll
        for (int j = 0; j < 16; j++) if (r[j] != 0) { mask |= 1u << j; my++; }
    }
    __shared__ int sc[256];
    sc[t] = my;
    __syncthreads();
    for (int d = 1; d < 256; d <<= 1) {
        int v = (t >= d) ? sc[t - d] : 0;
        __syncthreads();
        sc[t] += v;
        __syncthreads();
    }
    int pos = sc[t] - my;
    for (int j = 0; j < 16; j++) {
        if (mask & (1u << j)) {
            if (pos < MAXN) idx[(size_t)row * MAXN + pos] = c0 + j;
            pos++;
        }
    }
    if (t == 0) { int total = sc[255]; cnt[row] = (total < MAXN) ? total : MAXN; }
}

// ---- bf16-input path: X = feat @ weight1 via 1-term v_mfma_f32_32x32x16_bf16 ----
// Grid (128, 2): 32-row tile per block, 8 waves = 8 K-eighths, LDS reduce, plain store.
// A frag: lane row=l&31, k=(l>>5)*8+j. B frag: lane col=l&31, k=(l>>5)*8+j.
// D: col=l&31, row=(reg&3)+8*(reg>>2)+4*(l>>5).
__global__ __launch_bounds__(512) void k_featgemm_mfma(const int* __restrict__ flag,
    const void* __restrict__ F0v, const void* __restrict__ F1v,
    const u16* __restrict__ BtH, float* __restrict__ X0, float* __restrict__ X1)
{
    if (*flag) return;                     // f32 mode: handled by k_featgemm_mfma_f32
    const u16* F = (const u16*)(blockIdx.y ? F1v : F0v);
    float* X = blockIdx.y ? X1 : X0;
    int r0 = blockIdx.x * 32;
    int tid = threadIdx.x;
    int w  = tid >> 6;                     // wave id = K-eighth
    int l  = tid & 63;
    int lr = l & 31;                       // A row / B col / D col
    int kg = l >> 5;                       // k-group (0..1), 8 elems each
    const u16* arow = F   + (size_t)(r0 + lr) * FIN + kg * 8;
    const u16* b0p  = BtH + (size_t)lr * 3008 + kg * 8;
    const u16* b1p  = BtH + (size_t)(lr + 32) * 3008 + kg * 8;
    f32x16 acc0 = fzero16(), acc1 = fzero16();
    #pragma unroll 4
    for (int s = w; s < 188; s += 8) {
        int kk = s * 16;
        bf16x8 a;
        if (kk + kg * 8 < FIN) a = *(const bf16x8*)(arow + kk);
        else                   a = bzero8();
        bf16x8 b0 = *(const bf16x8*)(b0p + kk);   // Bt zero-padded to 3008
        bf16x8 b1 = *(const bf16x8*)(b1p + kk);
        acc0 = __builtin_amdgcn_mfma_f32_32x32x16_bf16(a, b0, acc0, 0, 0, 0);
        acc1 = __builtin_amdgcn_mfma_f32_32x32x16_bf16(a, b1, acc1, 0, 0, 0);
    }
    __shared__ float red[8][2048];         // 64 KB: per-wave 32x64 partials
    float* rp = red[w];
    #pragma unroll
    for (int reg = 0; reg < 16; reg++) {
        int row = (reg & 3) + 8 * (reg >> 2) + 4 * kg;
        rp[row * 64 + lr] = acc0[reg];
    }
    #pragma unroll
    for (int reg = 0; reg < 16; reg++) {
        int row = (reg & 3) + 8 * (reg >> 2) + 4 * kg;
        rp[row * 64 + 32 + lr] = acc1[reg];
    }
    __syncthreads();
    for (int i = tid; i < 2048; i += 512) {
        float s0 = 0.f;
        #pragma unroll
        for (int j = 0; j < 8; j++) s0 += red[j][i];
        X[(size_t)r0 * 64 + i] = s0;
    }
}

// ---- f32-input path: X = feat @ weight1 via split-bf16 3-term MFMA ----
// a = ah + al (exact residual); acc += ah*bh + al*bh + ah*bl; dropped al*bl ~ 2^-18.
__global__ __launch_bounds__(512) void k_featgemm_mfma_f32(const int* __restrict__ flag,
    const void* __restrict__ F0v, const void* __restrict__ F1v,
    const u16* __restrict__ BtH, const u16* __restrict__ BtL,
    float* __restrict__ X0, float* __restrict__ X1)
{
    if (!*flag) return;                    // bf16 mode: handled by k_featgemm_mfma
    const float* F = (const float*)(blockIdx.y ? F1v : F0v);
    float* X = blockIdx.y ? X1 : X0;
    int r0 = blockIdx.x * 32;
    int tid = threadIdx.x;
    int w  = tid >> 6;                     // wave id = K-eighth
    int l  = tid & 63;
    int lr = l & 31;                       // A row / B col / D col
    int kg = l >> 5;                       // k-group (0..1), 8 elems each
    const float* arow = F + (size_t)(r0 + lr) * FIN + kg * 8;
    const u16* b0h = BtH + (size_t)lr * 3008 + kg * 8;
    const u16* b1h = BtH + (size_t)(lr + 32) * 3008 + kg * 8;
    const u16* b0l = BtL + (size_t)lr * 3008 + kg * 8;
    const u16* b1l = BtL + (size_t)(lr + 32) * 3008 + kg * 8;
    f32x16 acc0 = fzero16(), acc1 = fzero16();
    #pragma unroll 2
    for (int s = w; s < 188; s += 8) {
        int kk = s * 16;
        float av[8];
        if (kk + kg * 8 < FIN) {
            float4 p0 = *(const float4*)(arow + kk);
            float4 p1 = *(const float4*)(arow + kk + 4);
            av[0] = p0.x; av[1] = p0.y; av[2] = p0.z; av[3] = p0.w;
            av[4] = p1.x; av[5] = p1.y; av[6] = p1.z; av[7] = p1.w;
        } else {
            #pragma unroll
            for (int j = 0; j < 8; j++) av[j] = 0.f;
        }
        bf16x8 ah, al;
        #pragma unroll
        for (int j = 0; j < 8; j++) {
            __bf16 hv = (__bf16)av[j];
            float  rv = av[j] - (float)hv;       // exact
            ah[j] = hv;
            al[j] = (__bf16)rv;
        }
        bf16x8 v0h = *(const bf16x8*)(b0h + kk);
        bf16x8 v1h = *(const bf16x8*)(b1h + kk);
        bf16x8 v0l = *(const bf16x8*)(b0l + kk);
        bf16x8 v1l = *(const bf16x8*)(b1l + kk);
        acc0 = __builtin_amdgcn_mfma_f32_32x32x16_bf16(ah, v0h, acc0, 0, 0, 0);
        acc0 = __builtin_amdgcn_mfma_f32_32x32x16_bf16(al, v0h, acc0, 0, 0, 0);
        acc0 = __builtin_amdgcn_mfma_f32_32x32x16_bf16(ah, v0l, acc0, 0, 0, 0);
        acc1 = __builtin_amdgcn_mfma_f32_32x32x16_bf16(ah, v1h, acc1, 0, 0, 0);
        acc1 = __builtin_amdgcn_mfma_f32_32x32x16_bf16(al, v1h, acc1, 0, 0, 0);
        acc1 = __builtin_amdgcn_mfma_f32_32x32x16_bf16(ah, v1l, acc1, 0, 0, 0);
    }
    __shared__ float red[8][2048];         // 64 KB: per-wave 32x64 partials
    float* rp = red[w];
    #pragma unroll
    for (int reg = 0; reg < 16; reg++) {
        int row = (reg & 3) + 8 * (reg >> 2) + 4 * kg;
        rp[row * 64 + lr] = acc0[reg];
    }
    #pragma unroll
    for (int reg = 0; reg < 16; reg++) {
        int row = (reg & 3) + 8 * (reg >> 2) + 4 * kg;
        rp[row * 64 + 32 + lr] = acc1[reg];
    }
    __syncthreads();
    for (int i = tid; i < 2048; i += 512) {
        float s0 = 0.f;
        #pragma unroll
        for (int j = 0; j < 8; j++) s0 += red[j][i];
        X[(size_t)r0 * 64 + i] = s0;
    }
}

// ---- Wh = X @ att_W; s = Wh@a_src; d = Wh@a_dst (all-f32) ----
__global__ __launch_bounds__(64) void k_whsd(
    const float* __restrict__ X1, const float* __restrict__ X2,
    const float* __restrict__ AW, const float* __restrict__ asrc, const float* __restrict__ adst,
    float* __restrict__ Wh1, float* __restrict__ Wh2,
    float* __restrict__ s1, float* __restrict__ s2,
    float* __restrict__ d1, float* __restrict__ d2)
{
    const float* X = blockIdx.y ? X2 : X1;
    float* Wh = blockIdx.y ? Wh2 : Wh1;
    float* sv = blockIdx.y ? s2 : s1;
    float* dv = blockIdx.y ? d2 : d1;
    int row = blockIdx.x, c = threadIdx.x;
    __shared__ float x[64];
    x[c] = X[(size_t)row * 64 + c];
    __syncthreads();
    float acc = 0.f;
    #pragma unroll 16
    for (int k = 0; k < 64; k++) acc += x[k] * AW[k * 64 + c];
    Wh[(size_t)row * 64 + c] = acc;
    float vs = acc * asrc[c];
    float vd = acc * adst[c];
    #pragma unroll
    for (int off = 32; off > 0; off >>= 1) { vs += __shfl_down(vs, off); vd += __shfl_down(vd, off); }
    if (c == 0) { sv[row] = vs; dv[row] = vd; }
}

// ---- masked softmax (rank-1 scores) + P @ Wh over CSR neighbors ----
__global__ __launch_bounds__(128) void k_attn(
    const int* __restrict__ cnt, const int* __restrict__ idx,
    const float* __restrict__ s1, const float* __restrict__ s2,
    const float* __restrict__ d1, const float* __restrict__ d2,
    const float* __restrict__ Wh1, const float* __restrict__ Wh2,
    float* __restrict__ A1, float* __restrict__ A2)
{
    const float* sp = blockIdx.y ? s2 : s1;
    const float* dp = blockIdx.y ? d2 : d1;
    const float* Wh = blockIdx.y ? Wh2 : Wh1;
    float* A = blockIdx.y ? A2 : A1;
    int row = blockIdx.x, tid = threadIdx.x;
    int n = cnt[row];
    __shared__ int js[MAXN];
    __shared__ float ps[MAXN];
    __shared__ float red2[2];
    __shared__ float ared[2][64];
    for (int k = tid; k < n; k += 128) js[k] = idx[(size_t)row * MAXN + k];
    __syncthreads();
    float si = sp[row];
    float m = -3.0e38f;
    for (int k = tid; k < n; k += 128) {
        float e = si + dp[js[k]];
        e = e > 0.f ? e : 0.2f * e;   // LeakyReLU(0.2)
        ps[k] = e;
        m = fmaxf(m, e);
    }
    #pragma unroll
    for (int off = 32; off > 0; off >>= 1) m = fmaxf(m, __shfl_down(m, off));
    if ((tid & 63) == 0) red2[tid >> 6] = m;
    __syncthreads();
    m = fmaxf(red2[0], red2[1]);
    __syncthreads();
    float zz = 0.f;
    for (int k = tid; k < n; k += 128) {
        float p = __expf(ps[k] - m);
        ps[k] = p;
        zz += p;
    }
    #pragma unroll
    for (int off = 32; off > 0; off >>= 1) zz += __shfl_down(zz, off);
    if ((tid & 63) == 0) red2[tid >> 6] = zz;
    __syncthreads();
    float Z = red2[0] + red2[1];
    Z = fmaxf(Z, 1e-20f);           // guard 0/0
    int f = tid & 63, half = tid >> 6;
    float acc = 0.f;
    for (int k = half; k < n; k += 2) acc += ps[k] * Wh[(size_t)js[k] * 64 + f];
    ared[half][f] = acc;
    __syncthreads();
    if (tid < 64) A[(size_t)row * 64 + f] = (ared[0][f] + ared[1][f]) / Z;
}

// ---- 3-layer MLP 64->256->128->64; 4 rows/block; writes z (f32) and hiden_emb (dual-dtype, y==0) ----
__global__ __launch_bounds__(256) void k_mlp(const int* __restrict__ flag,
    const float* __restrict__ A1, const float* __restrict__ A2,
    const float* __restrict__ W1, const float* __restrict__ b1,
    const float* __restrict__ W2, const float* __restrict__ b2,
    const float* __restrict__ W3, const float* __restrict__ b3,
    float* __restrict__ Z1, float* __restrict__ Z2, void* __restrict__ hidenv)
{
    const float* A = blockIdx.y ? A2 : A1;
    float* Z = blockIdx.y ? Z2 : Z1;
    int row0 = blockIdx.x * 4, tid = threadIdx.x;
    __shared__ float x[4][64], h1[4][256], h2[4][128];
    {
        int r = tid >> 6, c = tid & 63;
        x[r][c] = A[(size_t)(row0 + r) * 64 + c];
    }
    __syncthreads();
    {
        float a0 = b1[tid], a1v = a0, a2v = a0, a3v = a0;
        #pragma unroll 8
        for (int k = 0; k < 64; k++) {
            float w = W1[k * 256 + tid];
            a0 += x[0][k] * w; a1v += x[1][k] * w; a2v += x[2][k] * w; a3v += x[3][k] * w;
        }
        h1[0][tid] = fmaxf(a0, 0.f);  h1[1][tid] = fmaxf(a1v, 0.f);
        h1[2][tid] = fmaxf(a2v, 0.f); h1[3][tid] = fmaxf(a3v, 0.f);
    }
    __syncthreads();
    if (tid < 128) {
        float a0 = b2[tid], a1v = a0, a2v = a0, a3v = a0;
        #pragma unroll 8
        for (int k = 0; k < 256; k++) {
            float w = W2[k * 128 + tid];
            a0 += h1[0][k] * w; a1v += h1[1][k] * w; a2v += h1[2][k] * w; a3v += h1[3][k] * w;
        }
        h2[0][tid] = fmaxf(a0, 0.f);  h2[1][tid] = fmaxf(a1v, 0.f);
        h2[2][tid] = fmaxf(a2v, 0.f); h2[3][tid] = fmaxf(a3v, 0.f);
    }
    __syncthreads();
    if (tid < 64) {
        float a[4];
        a[0] = a[1] = a[2] = a[3] = b3[tid];
        #pragma unroll 8
        for (int k = 0; k < 128; k++) {
            float w = W3[k * 64 + tid];
            a[0] += h2[0][k] * w; a[1] += h2[1][k] * w; a[2] += h2[2][k] * w; a[3] += h2[3][k] * w;
        }
        bool isf = (*flag != 0);
        #pragma unroll
        for (int r = 0; r < 4; r++) {
            size_t ei = (size_t)(row0 + r) * 64 + tid;
            Z[ei] = a[r];
            if (blockIdx.y == 0) {
                if (isf) ((float*)hidenv)[ei] = a[r];
                else     ((u16*)hidenv)[ei] = f2bf(a[r]);
            }
        }
    }
}

// ---- T = adj @ z over CSR ----
__global__ __launch_bounds__(64) void k_spmm(
    const int* __restrict__ cnt, const int* __restrict__ idx,
    const float* __restrict__ Z, float* __restrict__ T)
{
    int row = blockIdx.x, f = threadIdx.x;
    int n = cnt[row];
    const int* ir = idx + (size_t)row * MAXN;
    float acc = 0.f;
    for (int k = 0; k < n; k++) acc += Z[(size_t)ir[k] * 64 + f];
    T[(size_t)row * 64 + f] = acc;
}

// ---- H = T @ weight2 -> out (dual-dtype store), 8 rows/block ----
__global__ __launch_bounds__(256) void k_hgemm(const int* __restrict__ flag,
    const float* __restrict__ T, const float* __restrict__ W2f, void* __restrict__ outv)
{
    bool isf = (*flag != 0);
    int r0 = blockIdx.x * 8, tid = threadIdx.x;
    __shared__ float tt[8][64];
    for (int i = tid; i < 512; i += 256) tt[i >> 6][i & 63] = T[(size_t)r0 * 64 + i];
    __syncthreads();
    for (int c = tid; c < FIN; c += 256) {
        float a[8] = {0,0,0,0,0,0,0,0};
        #pragma unroll 8
        for (int k = 0; k < 64; k++) {
            float w = W2f[(size_t)k * FIN + c];
            #pragma unroll
            for (int i = 0; i < 8; i++) a[i] += tt[i][k] * w;
        }
        #pragma unroll
        for (int i = 0; i < 8; i++) {
            size_t ei = 262144 + (size_t)(r0 + i) * FIN + c;
            if (isf) ((float*)outv)[ei] = a[i];
            else     ((u16*)outv)[ei] = f2bf(a[i]);
        }
    }
}

// ---- readout: mean over graph_neigh nbrs of relu(z), L2 normalize, sigmoid ----
__global__ __launch_bounds__(64) void k_readout(
    const int* __restrict__ cnt, const int* __restrict__ idx,
    const float* __restrict__ Z1, const float* __restrict__ Z2,
    float* __restrict__ G1, float* __restrict__ G2)
{
    const float* Z = blockIdx.y ? Z2 : Z1;
    float* G = blockIdx.y ? G2 : G1;
    int row = blockIdx.x, f = threadIdx.x;
    int n = cnt[row];
    const int* ir = idx + (size_t)row * MAXN;
    float acc = 0.f;
    for (int k = 0; k < n; k++) acc += fmaxf(Z[(size_t)ir[k] * 64 + f], 0.f);
    acc /= (float)(n > 0 ? n : 1);
    float sq = acc * acc;
    #pragma unroll
    for (int off = 32; off > 0; off >>= 1) sq += __shfl_down(sq, off);
    sq = __shfl(sq, 0);
    float nrm = fmaxf(sqrtf(sq), 1e-12f);
    float v = acc / nrm;
    G[(size_t)row * 64 + f] = 1.f / (1.f + __expf(-v));
}

// ---- discriminator MLP 64->128->64; 4 rows/block; on {relu(z), relu(z_a), g, g_a} ----
__global__ __launch_bounds__(128) void k_dmlp(
    const float* __restrict__ z, const float* __restrict__ za,
    const float* __restrict__ g, const float* __restrict__ ga,
    const float* __restrict__ W1, const float* __restrict__ b1,
    const float* __restrict__ W2, const float* __restrict__ b2,
    float* __restrict__ De, float* __restrict__ Dea,
    float* __restrict__ Dg, float* __restrict__ Dga)
{
    int w = blockIdx.y;
    const float* X = (w == 0) ? z : (w == 1) ? za : (w == 2) ? g : ga;
    float* O = (w == 0) ? De : (w == 1) ? Dea : (w == 2) ? Dg : Dga;
    int doRelu = (w < 2);
    int row0 = blockIdx.x * 4, tid = threadIdx.x;
    __shared__ float x[4][64], h1[4][128];
    for (int i = tid; i < 256; i += 128) {
        int r = i >> 6, c = i & 63;
        float v = X[(size_t)(row0 + r) * 64 + c];
        x[r][c] = doRelu ? fmaxf(v, 0.f) : v;
    }
    __syncthreads();
    {
        float a0 = b1[tid], a1v = a0, a2v = a0, a3v = a0;
        #pragma unroll 8
        for (int k = 0; k < 64; k++) {
            float w_ = W1[k * 128 + tid];
            a0 += x[0][k] * w_; a1v += x[1][k] * w_; a2v += x[2][k] * w_; a3v += x[3][k] * w_;
        }
        h1[0][tid] = fmaxf(a0, 0.f);  h1[1][tid] = fmaxf(a1v, 0.f);
        h1[2][tid] = fmaxf(a2v, 0.f); h1[3][tid] = fmaxf(a3v, 0.f);
    }
    __syncthreads();
    if (tid < 64) {
        float a[4];
        a[0] = a[1] = a[2] = a[3] = b2[tid];
        #pragma unroll 8
        for (int k = 0; k < 128; k++) {
            float w_ = W2[k * 64 + tid];
            a[0] += h1[0][k] * w_; a[1] += h1[1][k] * w_; a[2] += h1[2][k] * w_; a[3] += h1[3][k] * w_;
        }
        #pragma unroll
        for (int r = 0; r < 4; r++) O[(size_t)(row0 + r) * 64 + tid] = a[r];
    }
}

// ---- bilinear: out = x . (bil_W @ y) + b ; dual-dtype store ----
__global__ __launch_bounds__(64) void k_bilin(const int* __restrict__ flag,
    const float* __restrict__ De, const float* __restrict__ Dea,
    const float* __restrict__ Dg, const float* __restrict__ Dga,
    const float* __restrict__ BW, const float* __restrict__ bb, void* __restrict__ outv)
{
    int w = blockIdx.y;
    const float* X = (w == 0 || w == 3) ? De : Dea;
    const float* Y = (w <= 1) ? Dg : Dga;
    size_t bse = (w <= 1) ? (size_t)12550144 : (size_t)12558336;
    int col = (w == 0 || w == 2) ? 0 : 1;
    int row = blockIdx.x, k = threadIdx.x;
    __shared__ float x[64], y[64];
    x[k] = X[(size_t)row * 64 + k];
    y[k] = Y[(size_t)row * 64 + k];
    __syncthreads();
    float wv = 0.f;
    #pragma unroll 8
    for (int j = 0; j < 64; j++) wv += BW[k * 64 + j] * y[j];
    float v = x[k] * wv;
    #pragma unroll
    for (int off = 32; off > 0; off >>= 1) v += __shfl_down(v, off);
    if (k == 0) {
        float r = v + bb[0];
        size_t ei = bse + (size_t)row * 2 + col;
        if (*flag) ((float*)outv)[ei] = r;
        else       ((u16*)outv)[ei] = f2bf(r);
    }
}

extern "C" void kernel_launch(void* const* d_in, const int* in_sizes, int n_in,
                              void* d_out, int out_size, void* d_ws, size_t ws_size,
                              hipStream_t stream) {
    const void* feat   = d_in[0];
    const void* feat_a = d_in[1];
    const void* adj    = d_in[2];
    const void* gn     = d_in[3];
    const void* w1     = d_in[4];
    const void* w2     = d_in[5];
    const void* attW   = d_in[6];
    const void* a_src  = d_in[7];
    const void* a_dst  = d_in[8];
    const void* mW1    = d_in[9];
    const void* mb1    = d_in[10];
    const void* mW2    = d_in[11];
    const void* mb2    = d_in[12];
    const void* mW3    = d_in[13];
    const void* mb3    = d_in[14];
    const void* dW1    = d_in[15];
    const void* db1    = d_in[16];
    const void* dW2    = d_in[17];
    const void* db2    = d_in[18];
    const void* bW     = d_in[19];
    const void* bb     = d_in[20];
    (void)in_sizes; (void)n_in; (void)out_size;

    // ---- d_ws: flag + T + w2f  (~1.8 MB total; minimal footprint) ----
    char* wsb = (char*)d_ws;
    int*   flag = (int*)wsb;                        // 4 B (pad 256)
    float* T    = (float*)(wsb + 256);              // 1,048,576 B
    float* w2f  = (float*)(wsb + 256 + 1048576);    // 768,000 B
    (void)ws_size;

    // ---- scratch arena at dtype-independent byte window of d_out:
    // bytes [1,048,576 , 21,200,000) lie inside the h output region for BOTH
    // bf16 (h bytes [524288,25100288)) and f32 (h bytes [1048576,50200576)),
    // and are fully overwritten by k_hgemm at the end.
    char* sc = (char*)d_out + 1048576;
    size_t soff = 0;
    auto salloc = [&](size_t nbytes) -> void* {
        void* p = (void*)(sc + soff);
        soff += (nbytes + 255) & ~(size_t)255;
        return p;
    };
    const size_t NV = (size_t)NN * 64;
    float* wA   = (float*)salloc((size_t)274689 * 4);  // 16-segment f32 weight arena
    int*   aCnt = (int*)salloc(NN * 4);
    int*   gCnt = (int*)salloc(NN * 4);
    int*   aIdx = (int*)salloc((size_t)NN * MAXN * 4);
    int*   gIdx = (int*)salloc((size_t)NN * MAXN * 4);
    float* X1  = (float*)salloc(NV * 4);
    float* X2  = (float*)salloc(NV * 4);   // contiguous with X1 (NV*4 is 256-mult)
    float* Wh1 = (float*)salloc(NV * 4);
    float* Wh2 = (float*)salloc(NV * 4);
    float* A1  = (float*)salloc(NV * 4);
    float* A2  = (float*)salloc(NV * 4);
    float* z   = (float*)salloc(NV * 4);
    float* za  = (float*)salloc(NV * 4);
    float* g   = (float*)salloc(NV * 4);
    float* ga  = (float*)salloc(NV * 4);
    float* De  = (float*)salloc(NV * 4);
    float* Dea = (float*)salloc(NV * 4);
    float* Dg  = (float*)salloc(NV * 4);
    float* Dga = (float*)salloc(NV * 4);
    float* s1  = (float*)salloc(NN * 4);
    float* s2  = (float*)salloc(NN * 4);
    float* d1  = (float*)salloc(NN * 4);
    float* d2  = (float*)salloc(NN * 4);
    // soff ~= 20.1 MB < 20.15 MB window: fits.

    float* w1f   = wA + 0;
    float* attWf = wA + 192000;
    float* asrcf = wA + 196096;
    float* adstf = wA + 196160;
    float* mW1f  = wA + 196224;
    float* mb1f  = wA + 212608;
    float* mW2f  = wA + 212864;
    float* mb2f  = wA + 245632;
    float* mW3f  = wA + 245760;
    float* mb3f  = wA + 253952;
    float* dW1f  = wA + 254016;
    float* db1f  = wA + 262208;
    float* dW2f  = wA + 262336;
    float* db2f  = wA + 270528;
    float* bWf   = wA + 270592;
    float* bbf   = wA + 274688;

    // BtH/BtL (split-bf16 W1^T [64][3008], 385 KB each) park in the De/Dea
    // slots: those are not written until k_dmlp, long after the feat GEMM.
    u16* BtH = (u16*)De;
    u16* BtL = (u16*)Dea;

    k_detect<<<1, 1024, 0, stream>>>((const u16*)feat, flag);
    k_convw<<<dim3(750, 16), 256, 0, stream>>>(flag,
        w1, attW, a_src, a_dst, mW1, mb1, mW2, mb2, mW3, mb3,
        dW1, db1, dW2, db2, bW, bb, wA);
    k_convw2<<<750, 256, 0, stream>>>(flag, w2, w2f);
    k_convw1t<<<752, 256, 0, stream>>>(flag, w1, BtH, BtL);
    k_build_csr<<<dim3(NN, 2), 256, 0, stream>>>(flag, adj, gn, aCnt, aIdx, gCnt, gIdx);
    k_featgemm_mfma<<<dim3(NN / 32, 2), 512, 0, stream>>>(flag, feat, feat_a, BtH, X1, X2);
    k_featgemm_mfma_f32<<<dim3(NN / 32, 2), 512, 0, stream>>>(flag, feat, feat_a, BtH, BtL, X1, X2);
    k_whsd<<<dim3(NN, 2), 64, 0, stream>>>(X1, X2, attWf, asrcf, adstf, Wh1, Wh2, s1, s2, d1, d2);
    k_attn<<<dim3(NN, 2), 128, 0, stream>>>(aCnt, aIdx, s1, s2, d1, d2, Wh1, Wh2, A1, A2);
    k_mlp<<<dim3(NN / 4, 2), 256, 0, stream>>>(flag, A1, A2, mW1f, mb1f, mW2f, mb2f, mW3f, mb3f, z, za, d_out);
    k_readout<<<dim3(NN, 2), 64, 0, stream>>>(gCnt, gIdx, z, za, g, ga);
    k_dmlp<<<dim3(NN / 4, 4), 128, 0, stream>>>(z, za, g, ga, dW1f, db1f, dW2f, db2f, De, Dea, Dg, Dga);
    k_bilin<<<dim3(NN, 4), 64, 0, stream>>>(flag, De, Dea, Dg, Dga, bWf, bbf, d_out);
    k_spmm<<<NN, 64, 0, stream>>>(aCnt, aIdx, z, T);
    k_hgemm<<<512, 256, 0, stream>>>(flag, T, w2f, d_out);   // overwrites arena with real h
}

// Round 3
// 471.182 us; speedup vs baseline: 1.2474x; 1.0482x over previous
//
#include <hip/hip_runtime.h>

#define NN   4096
#define FIN  3000
#define MAXN 128

typedef unsigned short u16;
typedef __bf16 bf16x8 __attribute__((ext_vector_type(8)));
typedef float f32x16 __attribute__((ext_vector_type(16)));

__device__ __forceinline__ float bf2f(u16 u) { union { unsigned int i; float f; } v; v.i = ((unsigned int)u) << 16; return v.f; }
__device__ __forceinline__ u16 f2bf(float f) {
    union { float f; unsigned int i; } v; v.f = f;
    return (u16)((v.i + 0x7FFFu + ((v.i >> 16) & 1u)) >> 16);
}
__device__ __forceinline__ bf16x8 bzero8() {
    union { unsigned long long q[2]; bf16x8 v; } u; u.q[0] = 0ull; u.q[1] = 0ull; return u.v;
}
__device__ __forceinline__ f32x16 fzero16() {
    f32x16 v;
    #pragma unroll
    for (int i = 0; i < 16; i++) v[i] = 0.f;
    return v;
}

// ---- dtype detector: bf16 N(0,1) u16s have exponent ~127; f32-as-u16 halves are random.
__global__ __launch_bounds__(1024) void k_detect(const u16* __restrict__ feat, int* __restrict__ flag)
{
    __shared__ int tot;
    if (threadIdx.x == 0) tot = 0;
    __syncthreads();
    int ins = 0;
    for (int i = threadIdx.x; i < 16384; i += 1024) {
        u16 u = feat[i];
        int e = (u >> 7) & 0xFF;
        if (u != 0 && (e < 90 || e > 160)) ins++;
    }
    atomicAdd(&tot, ins);
    __syncthreads();
    if (threadIdx.x == 0) *flag = (tot > 1024) ? 1 : 0;   // 1 = inputs are f32
}

// ---- convert 16 weight tensors -> f32 arena (blockIdx.y = segment) ----
__global__ __launch_bounds__(256) void k_convw(const int* __restrict__ flag,
    const void* s0, const void* s1, const void* s2, const void* s3,
    const void* s4, const void* s5, const void* s6, const void* s7,
    const void* s8, const void* s9, const void* s10, const void* s11,
    const void* s12, const void* s13, const void* s14, const void* s15,
    float* __restrict__ dst)
{
    const void* srcs[16] = {s0,s1,s2,s3,s4,s5,s6,s7,s8,s9,s10,s11,s12,s13,s14,s15};
    const int offs[16] = {0,192000,196096,196160,196224,212608,212864,245632,245760,253952,254016,262208,262336,270528,270592,274688};
    const int ns[16]   = {192000,4096,64,64,16384,256,32768,128,8192,64,8192,128,8192,64,4096,1};
    int seg = blockIdx.y;
    int i = blockIdx.x * 256 + threadIdx.x;
    if (i >= ns[seg]) return;
    float v = (*flag) ? ((const float*)srcs[seg])[i] : bf2f(((const u16*)srcs[seg])[i]);
    dst[offs[seg] + i] = v;
}

// ---- build W2tH/W2tL = split-bf16 W2^T [3008][64] (n-major), zero-padded in n ----
__global__ __launch_bounds__(256) void k_convw2t(const int* __restrict__ flag,
    const void* __restrict__ src, u16* __restrict__ WH, u16* __restrict__ WL)
{
    int i = blockIdx.x * 256 + threadIdx.x;      // over 3008*64
    if (i >= 3008 * 64) return;
    int n = i >> 6, k = i & 63;
    float v = 0.f;
    if (n < FIN)
        v = (*flag) ? ((const float*)src)[(size_t)k * FIN + n]
                    : bf2f(((const u16*)src)[(size_t)k * FIN + n]);
    u16 h = f2bf(v);
    float r = v - bf2f(h);                       // exact in f32
    WH[i] = h;
    WL[i] = f2bf(r);
}

// ---- build BtH/BtL = split-bf16 W1^T [64][3008], zero-padded in k ----
// v = hi + lo + O(2^-18 * v): hi = bf16(v), lo = bf16(v - hi) (exact residual).
__global__ __launch_bounds__(256) void k_convw1t(const int* __restrict__ flag,
    const void* __restrict__ w1src, u16* __restrict__ BtH, u16* __restrict__ BtL)
{
    int i = blockIdx.x * 256 + threadIdx.x;      // over 64*3008
    if (i >= 64 * 3008) return;
    int c = i / 3008, k = i - c * 3008;
    float v = 0.f;
    if (k < 3000)
        v = (*flag) ? ((const float*)w1src)[(size_t)k * 64 + c]
                    : bf2f(((const u16*)w1src)[(size_t)k * 64 + c]);
    u16 h = f2bf(v);
    float r = v - bf2f(h);                       // exact in f32
    BtH[(size_t)c * 3008 + k] = h;
    BtL[(size_t)c * 3008 + k] = f2bf(r);
}

// ---- ordered CSR build (prefix-scan, deterministic, sorted) for adj / graph_neigh ----
__global__ __launch_bounds__(256) void k_build_csr(const int* __restrict__ flag,
    const void* __restrict__ Av, const void* __restrict__ Gv,
    int* __restrict__ aCnt, int* __restrict__ aIdx,
    int* __restrict__ gCnt, int* __restrict__ gIdx)
{
    bool isf = (*flag != 0);
    const void* M = blockIdx.y ? Gv : Av;
    int* cnt = blockIdx.y ? gCnt : aCnt;
    int* idx = blockIdx.y ? gIdx : aIdx;
    int row = blockIdx.x, t = threadIdx.x;
    int c0 = t * 16;
    unsigned int mask = 0; int my = 0;
    if (isf) {
        const float* r = (const float*)M + (size_t)row * NN + c0;
        #pragma unroll
        for (int j = 0; j < 16; j++) if (r[j] != 0.f) { mask |= 1u << j; my++; }
    } else {
        const u16* r = (const u16*)M + (size_t)row * NN + c0;
        #pragma unroll
        for (int j = 0; j < 16; j++) if (r[j] != 0) { mask |= 1u << j; my++; }
    }
    __shared__ int sc[256];
    sc[t] = my;
    __syncthreads();
    for (int d = 1; d < 256; d <<= 1) {
        int v = (t >= d) ? sc[t - d] : 0;
        __syncthreads();
        sc[t] += v;
        __syncthreads();
    }
    int pos = sc[t] - my;
    for (int j = 0; j < 16; j++) {
        if (mask & (1u << j)) {
            if (pos < MAXN) idx[(size_t)row * MAXN + pos] = c0 + j;
            pos++;
        }
    }
    if (t == 0) { int total = sc[255]; cnt[row] = (total < MAXN) ? total : MAXN; }
}

// ---- bf16-input path: X = feat @ weight1 via 1-term v_mfma_f32_32x32x16_bf16 ----
// Grid (128, 2): 32-row tile per block, 8 waves = 8 K-eighths, LDS reduce, plain store.
// A frag: lane row=l&31, k=(l>>5)*8+j. B frag: lane col=l&31, k=(l>>5)*8+j.
// D: col=l&31, row=(reg&3)+8*(reg>>2)+4*(l>>5).
__global__ __launch_bounds__(512) void k_featgemm_mfma(const int* __restrict__ flag,
    const void* __restrict__ F0v, const void* __restrict__ F1v,
    const u16* __restrict__ BtH, float* __restrict__ X0, float* __restrict__ X1)
{
    if (*flag) return;                     // f32 mode: handled by k_featgemm_mfma_f32
    const u16* F = (const u16*)(blockIdx.y ? F1v : F0v);
    float* X = blockIdx.y ? X1 : X0;
    int r0 = blockIdx.x * 32;
    int tid = threadIdx.x;
    int w  = tid >> 6;                     // wave id = K-eighth
    int l  = tid & 63;
    int lr = l & 31;                       // A row / B col / D col
    int kg = l >> 5;                       // k-group (0..1), 8 elems each
    const u16* arow = F   + (size_t)(r0 + lr) * FIN + kg * 8;
    const u16* b0p  = BtH + (size_t)lr * 3008 + kg * 8;
    const u16* b1p  = BtH + (size_t)(lr + 32) * 3008 + kg * 8;
    f32x16 acc0 = fzero16(), acc1 = fzero16();
    #pragma unroll 4
    for (int s = w; s < 188; s += 8) {
        int kk = s * 16;
        bf16x8 a;
        if (kk + kg * 8 < FIN) a = *(const bf16x8*)(arow + kk);
        else                   a = bzero8();
        bf16x8 b0 = *(const bf16x8*)(b0p + kk);   // Bt zero-padded to 3008
        bf16x8 b1 = *(const bf16x8*)(b1p + kk);
        acc0 = __builtin_amdgcn_mfma_f32_32x32x16_bf16(a, b0, acc0, 0, 0, 0);
        acc1 = __builtin_amdgcn_mfma_f32_32x32x16_bf16(a, b1, acc1, 0, 0, 0);
    }
    __shared__ float red[8][2048];         // 64 KB: per-wave 32x64 partials
    float* rp = red[w];
    #pragma unroll
    for (int reg = 0; reg < 16; reg++) {
        int row = (reg & 3) + 8 * (reg >> 2) + 4 * kg;
        rp[row * 64 + lr] = acc0[reg];
    }
    #pragma unroll
    for (int reg = 0; reg < 16; reg++) {
        int row = (reg & 3) + 8 * (reg >> 2) + 4 * kg;
        rp[row * 64 + 32 + lr] = acc1[reg];
    }
    __syncthreads();
    for (int i = tid; i < 2048; i += 512) {
        float s0 = 0.f;
        #pragma unroll
        for (int j = 0; j < 8; j++) s0 += red[j][i];
        X[(size_t)r0 * 64 + i] = s0;
    }
}

// ---- f32-input path: X = feat @ weight1 via split-bf16 3-term MFMA ----
// a = ah + al (exact residual); acc += ah*bh + al*bh + ah*bl; dropped al*bl ~ 2^-18.
// 2-way K-split across blockIdx.z (16 K-slots total) for 4 waves/SIMD occupancy;
// atomicAdd epilogue into memset X (4 MB atomic traffic).
__global__ __launch_bounds__(512) void k_featgemm_mfma_f32(const int* __restrict__ flag,
    const void* __restrict__ F0v, const void* __restrict__ F1v,
    const u16* __restrict__ BtH, const u16* __restrict__ BtL,
    float* __restrict__ X0, float* __restrict__ X1)
{
    if (!*flag) return;                    // bf16 mode: handled by k_featgemm_mfma
    const float* F = (const float*)(blockIdx.y ? F1v : F0v);
    float* X = blockIdx.y ? X1 : X0;
    int r0 = blockIdx.x * 32;
    int tid = threadIdx.x;
    int w  = tid >> 6;                     // wave id
    int l  = tid & 63;
    int lr = l & 31;                       // A row / B col / D col
    int kg = l >> 5;                       // k-group (0..1), 8 elems each
    int s0 = blockIdx.z * 8 + w;           // K-slot 0..15
    const float* arow = F + (size_t)(r0 + lr) * FIN + kg * 8;
    const u16* b0h = BtH + (size_t)lr * 3008 + kg * 8;
    const u16* b1h = BtH + (size_t)(lr + 32) * 3008 + kg * 8;
    const u16* b0l = BtL + (size_t)lr * 3008 + kg * 8;
    const u16* b1l = BtL + (size_t)(lr + 32) * 3008 + kg * 8;
    f32x16 acc0 = fzero16(), acc1 = fzero16();
    #pragma unroll 2
    for (int s = s0; s < 188; s += 16) {
        int kk = s * 16;
        float av[8];
        if (kk + kg * 8 < FIN) {
            float4 p0 = *(const float4*)(arow + kk);
            float4 p1 = *(const float4*)(arow + kk + 4);
            av[0] = p0.x; av[1] = p0.y; av[2] = p0.z; av[3] = p0.w;
            av[4] = p1.x; av[5] = p1.y; av[6] = p1.z; av[7] = p1.w;
        } else {
            #pragma unroll
            for (int j = 0; j < 8; j++) av[j] = 0.f;
        }
        bf16x8 ah, al;
        #pragma unroll
        for (int j = 0; j < 8; j++) {
            __bf16 hv = (__bf16)av[j];
            float  rv = av[j] - (float)hv;       // exact
            ah[j] = hv;
            al[j] = (__bf16)rv;
        }
        bf16x8 v0h = *(const bf16x8*)(b0h + kk);
        bf16x8 v1h = *(const bf16x8*)(b1h + kk);
        bf16x8 v0l = *(const bf16x8*)(b0l + kk);
        bf16x8 v1l = *(const bf16x8*)(b1l + kk);
        acc0 = __builtin_amdgcn_mfma_f32_32x32x16_bf16(ah, v0h, acc0, 0, 0, 0);
        acc0 = __builtin_amdgcn_mfma_f32_32x32x16_bf16(al, v0h, acc0, 0, 0, 0);
        acc0 = __builtin_amdgcn_mfma_f32_32x32x16_bf16(ah, v0l, acc0, 0, 0, 0);
        acc1 = __builtin_amdgcn_mfma_f32_32x32x16_bf16(ah, v1h, acc1, 0, 0, 0);
        acc1 = __builtin_amdgcn_mfma_f32_32x32x16_bf16(al, v1h, acc1, 0, 0, 0);
        acc1 = __builtin_amdgcn_mfma_f32_32x32x16_bf16(ah, v1l, acc1, 0, 0, 0);
    }
    __shared__ float red[8][2048];         // 64 KB: per-wave 32x64 partials
    float* rp = red[w];
    #pragma unroll
    for (int reg = 0; reg < 16; reg++) {
        int row = (reg & 3) + 8 * (reg >> 2) + 4 * kg;
        rp[row * 64 + lr] = acc0[reg];
    }
    #pragma unroll
    for (int reg = 0; reg < 16; reg++) {
        int row = (reg & 3) + 8 * (reg >> 2) + 4 * kg;
        rp[row * 64 + 32 + lr] = acc1[reg];
    }
    __syncthreads();
    for (int i = tid; i < 2048; i += 512) {
        float s0s = 0.f;
        #pragma unroll
        for (int j = 0; j < 8; j++) s0s += red[j][i];
        atomicAdd(&X[(size_t)r0 * 64 + i], s0s);
    }
}

// ---- Wh = X @ att_W; s = Wh@a_src; d = Wh@a_dst (all-f32) ----
__global__ __launch_bounds__(64) void k_whsd(
    const float* __restrict__ X1, const float* __restrict__ X2,
    const float* __restrict__ AW, const float* __restrict__ asrc, const float* __restrict__ adst,
    float* __restrict__ Wh1, float* __restrict__ Wh2,
    float* __restrict__ s1, float* __restrict__ s2,
    float* __restrict__ d1, float* __restrict__ d2)
{
    const float* X = blockIdx.y ? X2 : X1;
    float* Wh = blockIdx.y ? Wh2 : Wh1;
    float* sv = blockIdx.y ? s2 : s1;
    float* dv = blockIdx.y ? d2 : d1;
    int row = blockIdx.x, c = threadIdx.x;
    __shared__ float x[64];
    x[c] = X[(size_t)row * 64 + c];
    __syncthreads();
    float acc = 0.f;
    #pragma unroll 16
    for (int k = 0; k < 64; k++) acc += x[k] * AW[k * 64 + c];
    Wh[(size_t)row * 64 + c] = acc;
    float vs = acc * asrc[c];
    float vd = acc * adst[c];
    #pragma unroll
    for (int off = 32; off > 0; off >>= 1) { vs += __shfl_down(vs, off); vd += __shfl_down(vd, off); }
    if (c == 0) { sv[row] = vs; dv[row] = vd; }
}

// ---- masked softmax (rank-1 scores) + P @ Wh over CSR neighbors ----
__global__ __launch_bounds__(128) void k_attn(
    const int* __restrict__ cnt, const int* __restrict__ idx,
    const float* __restrict__ s1, const float* __restrict__ s2,
    const float* __restrict__ d1, const float* __restrict__ d2,
    const float* __restrict__ Wh1, const float* __restrict__ Wh2,
    float* __restrict__ A1, float* __restrict__ A2)
{
    const float* sp = blockIdx.y ? s2 : s1;
    const float* dp = blockIdx.y ? d2 : d1;
    const float* Wh = blockIdx.y ? Wh2 : Wh1;
    float* A = blockIdx.y ? A2 : A1;
    int row = blockIdx.x, tid = threadIdx.x;
    int n = cnt[row];
    __shared__ int js[MAXN];
    __shared__ float ps[MAXN];
    __shared__ float red2[2];
    __shared__ float ared[2][64];
    for (int k = tid; k < n; k += 128) js[k] = idx[(size_t)row * MAXN + k];
    __syncthreads();
    float si = sp[row];
    float m = -3.0e38f;
    for (int k = tid; k < n; k += 128) {
        float e = si + dp[js[k]];
        e = e > 0.f ? e : 0.2f * e;   // LeakyReLU(0.2)
        ps[k] = e;
        m = fmaxf(m, e);
    }
    #pragma unroll
    for (int off = 32; off > 0; off >>= 1) m = fmaxf(m, __shfl_down(m, off));
    if ((tid & 63) == 0) red2[tid >> 6] = m;
    __syncthreads();
    m = fmaxf(red2[0], red2[1]);
    __syncthreads();
    float zz = 0.f;
    for (int k = tid; k < n; k += 128) {
        float p = __expf(ps[k] - m);
        ps[k] = p;
        zz += p;
    }
    #pragma unroll
    for (int off = 32; off > 0; off >>= 1) zz += __shfl_down(zz, off);
    if ((tid & 63) == 0) red2[tid >> 6] = zz;
    __syncthreads();
    float Z = red2[0] + red2[1];
    Z = fmaxf(Z, 1e-20f);           // guard 0/0
    int f = tid & 63, half = tid >> 6;
    float acc = 0.f;
    for (int k = half; k < n; k += 2) acc += ps[k] * Wh[(size_t)js[k] * 64 + f];
    ared[half][f] = acc;
    __syncthreads();
    if (tid < 64) A[(size_t)row * 64 + f] = (ared[0][f] + ared[1][f]) / Z;
}

// ---- 3-layer MLP 64->256->128->64; 4 rows/block; writes z (f32) and hiden_emb (dual-dtype, y==0) ----
__global__ __launch_bounds__(256) void k_mlp(const int* __restrict__ flag,
    const float* __restrict__ A1, const float* __restrict__ A2,
    const float* __restrict__ W1, const float* __restrict__ b1,
    const float* __restrict__ W2, const float* __restrict__ b2,
    const float* __restrict__ W3, const float* __restrict__ b3,
    float* __restrict__ Z1, float* __restrict__ Z2, void* __restrict__ hidenv)
{
    const float* A = blockIdx.y ? A2 : A1;
    float* Z = blockIdx.y ? Z2 : Z1;
    int row0 = blockIdx.x * 4, tid = threadIdx.x;
    __shared__ float x[4][64], h1[4][256], h2[4][128];
    {
        int r = tid >> 6, c = tid & 63;
        x[r][c] = A[(size_t)(row0 + r) * 64 + c];
    }
    __syncthreads();
    {
        float a0 = b1[tid], a1v = a0, a2v = a0, a3v = a0;
        #pragma unroll 8
        for (int k = 0; k < 64; k++) {
            float w = W1[k * 256 + tid];
            a0 += x[0][k] * w; a1v += x[1][k] * w; a2v += x[2][k] * w; a3v += x[3][k] * w;
        }
        h1[0][tid] = fmaxf(a0, 0.f);  h1[1][tid] = fmaxf(a1v, 0.f);
        h1[2][tid] = fmaxf(a2v, 0.f); h1[3][tid] = fmaxf(a3v, 0.f);
    }
    __syncthreads();
    if (tid < 128) {
        float a0 = b2[tid], a1v = a0, a2v = a0, a3v = a0;
        #pragma unroll 8
        for (int k = 0; k < 256; k++) {
            float w = W2[k * 128 + tid];
            a0 += h1[0][k] * w; a1v += h1[1][k] * w; a2v += h1[2][k] * w; a3v += h1[3][k] * w;
        }
        h2[0][tid] = fmaxf(a0, 0.f);  h2[1][tid] = fmaxf(a1v, 0.f);
        h2[2][tid] = fmaxf(a2v, 0.f); h2[3][tid] = fmaxf(a3v, 0.f);
    }
    __syncthreads();
    if (tid < 64) {
        float a[4];
        a[0] = a[1] = a[2] = a[3] = b3[tid];
        #pragma unroll 8
        for (int k = 0; k < 128; k++) {
            float w = W3[k * 64 + tid];
            a[0] += h2[0][k] * w; a[1] += h2[1][k] * w; a[2] += h2[2][k] * w; a[3] += h2[3][k] * w;
        }
        bool isf = (*flag != 0);
        #pragma unroll
        for (int r = 0; r < 4; r++) {
            size_t ei = (size_t)(row0 + r) * 64 + tid;
            Z[ei] = a[r];
            if (blockIdx.y == 0) {
                if (isf) ((float*)hidenv)[ei] = a[r];
                else     ((u16*)hidenv)[ei] = f2bf(a[r]);
            }
        }
    }
}

// ---- T = adj @ z over CSR ----
__global__ __launch_bounds__(64) void k_spmm(
    const int* __restrict__ cnt, const int* __restrict__ idx,
    const float* __restrict__ Z, float* __restrict__ T)
{
    int row = blockIdx.x, f = threadIdx.x;
    int n = cnt[row];
    const int* ir = idx + (size_t)row * MAXN;
    float acc = 0.f;
    for (int k = 0; k < n; k++) acc += Z[(size_t)ir[k] * 64 + f];
    T[(size_t)row * 64 + f] = acc;
}

// ---- H = T @ weight2 via split-bf16 3-term MFMA -> out (dual-dtype store) ----
// Grid (128, 24), 256 thr = 4 waves; wave w owns col-tile ct = by*4+w (94 tiles).
// A frag from T rows (f32, in-register split); B frag from W2t[3008][64] H/L.
// No LDS, no barriers; plain coalesced stores (~49 MB -> write-BW bound).
__global__ __launch_bounds__(256) void k_hgemm_mfma(const int* __restrict__ flag,
    const float* __restrict__ T, const u16* __restrict__ WH, const u16* __restrict__ WL,
    void* __restrict__ outv)
{
    bool isf = (*flag != 0);
    int tid = threadIdx.x;
    int w = tid >> 6, l = tid & 63, lr = l & 31, kg = l >> 5;
    int ct = blockIdx.y * 4 + w;
    if (ct >= 94) return;                  // wave-uniform; no barriers in kernel
    int r0 = blockIdx.x * 32, c0 = ct * 32;
    const float* tp = T + (size_t)(r0 + lr) * 64 + kg * 8;
    bf16x8 ah[4], al[4];
    #pragma unroll
    for (int s = 0; s < 4; s++) {
        float4 p0 = *(const float4*)(tp + s * 16);
        float4 p1 = *(const float4*)(tp + s * 16 + 4);
        float av[8] = {p0.x, p0.y, p0.z, p0.w, p1.x, p1.y, p1.z, p1.w};
        #pragma unroll
        for (int j = 0; j < 8; j++) {
            __bf16 hv = (__bf16)av[j];
            ah[s][j] = hv;
            al[s][j] = (__bf16)(av[j] - (float)hv);   // exact residual
        }
    }
    const u16* bh = WH + (size_t)(c0 + lr) * 64 + kg * 8;
    const u16* bl = WL + (size_t)(c0 + lr) * 64 + kg * 8;
    f32x16 acc = fzero16();
    #pragma unroll
    for (int s = 0; s < 4; s++) {
        bf16x8 vh = *(const bf16x8*)(bh + s * 16);
        bf16x8 vl = *(const bf16x8*)(bl + s * 16);
        acc = __builtin_amdgcn_mfma_f32_32x32x16_bf16(ah[s], vh, acc, 0, 0, 0);
        acc = __builtin_amdgcn_mfma_f32_32x32x16_bf16(al[s], vh, acc, 0, 0, 0);
        acc = __builtin_amdgcn_mfma_f32_32x32x16_bf16(ah[s], vl, acc, 0, 0, 0);
    }
    int col = c0 + lr;
    bool cok = col < FIN;
    #pragma unroll
    for (int reg = 0; reg < 16; reg++) {
        int row = (reg & 3) + 8 * (reg >> 2) + 4 * kg;
        size_t ei = 262144 + (size_t)(r0 + row) * FIN + col;
        if (cok) {
            if (isf) ((float*)outv)[ei] = acc[reg];
            else     ((u16*)outv)[ei] = f2bf(acc[reg]);
        }
    }
}

// ---- readout: mean over graph_neigh nbrs of relu(z), L2 normalize, sigmoid ----
__global__ __launch_bounds__(64) void k_readout(
    const int* __restrict__ cnt, const int* __restrict__ idx,
    const float* __restrict__ Z1, const float* __restrict__ Z2,
    float* __restrict__ G1, float* __restrict__ G2)
{
    const float* Z = blockIdx.y ? Z2 : Z1;
    float* G = blockIdx.y ? G2 : G1;
    int row = blockIdx.x, f = threadIdx.x;
    int n = cnt[row];
    const int* ir = idx + (size_t)row * MAXN;
    float acc = 0.f;
    for (int k = 0; k < n; k++) acc += fmaxf(Z[(size_t)ir[k] * 64 + f], 0.f);
    acc /= (float)(n > 0 ? n : 1);
    float sq = acc * acc;
    #pragma unroll
    for (int off = 32; off > 0; off >>= 1) sq += __shfl_down(sq, off);
    sq = __shfl(sq, 0);
    float nrm = fmaxf(sqrtf(sq), 1e-12f);
    float v = acc / nrm;
    G[(size_t)row * 64 + f] = 1.f / (1.f + __expf(-v));
}

// ---- discriminator MLP 64->128->64; 4 rows/block; on {relu(z), relu(z_a), g, g_a} ----
__global__ __launch_bounds__(128) void k_dmlp(
    const float* __restrict__ z, const float* __restrict__ za,
    const float* __restrict__ g, const float* __restrict__ ga,
    const float* __restrict__ W1, const float* __restrict__ b1,
    const float* __restrict__ W2, const float* __restrict__ b2,
    float* __restrict__ De, float* __restrict__ Dea,
    float* __restrict__ Dg, float* __restrict__ Dga)
{
    int w = blockIdx.y;
    const float* X = (w == 0) ? z : (w == 1) ? za : (w == 2) ? g : ga;
    float* O = (w == 0) ? De : (w == 1) ? Dea : (w == 2) ? Dg : Dga;
    int doRelu = (w < 2);
    int row0 = blockIdx.x * 4, tid = threadIdx.x;
    __shared__ float x[4][64], h1[4][128];
    for (int i = tid; i < 256; i += 128) {
        int r = i >> 6, c = i & 63;
        float v = X[(size_t)(row0 + r) * 64 + c];
        x[r][c] = doRelu ? fmaxf(v, 0.f) : v;
    }
    __syncthreads();
    {
        float a0 = b1[tid], a1v = a0, a2v = a0, a3v = a0;
        #pragma unroll 8
        for (int k = 0; k < 64; k++) {
            float w_ = W1[k * 128 + tid];
            a0 += x[0][k] * w_; a1v += x[1][k] * w_; a2v += x[2][k] * w_; a3v += x[3][k] * w_;
        }
        h1[0][tid] = fmaxf(a0, 0.f);  h1[1][tid] = fmaxf(a1v, 0.f);
        h1[2][tid] = fmaxf(a2v, 0.f); h1[3][tid] = fmaxf(a3v, 0.f);
    }
    __syncthreads();
    if (tid < 64) {
        float a[4];
        a[0] = a[1] = a[2] = a[3] = b2[tid];
        #pragma unroll 8
        for (int k = 0; k < 128; k++) {
            float w_ = W2[k * 64 + tid];
            a[0] += h1[0][k] * w_; a[1] += h1[1][k] * w_; a[2] += h1[2][k] * w_; a[3] += h1[3][k] * w_;
        }
        #pragma unroll
        for (int r = 0; r < 4; r++) O[(size_t)(row0 + r) * 64 + tid] = a[r];
    }
}

// ---- bilinear: out = x . (bil_W @ y) + b ; dual-dtype store ----
__global__ __launch_bounds__(64) void k_bilin(const int* __restrict__ flag,
    const float* __restrict__ De, const float* __restrict__ Dea,
    const float* __restrict__ Dg, const float* __restrict__ Dga,
    const float* __restrict__ BW, const float* __restrict__ bb, void* __restrict__ outv)
{
    int w = blockIdx.y;
    const float* X = (w == 0 || w == 3) ? De : Dea;
    const float* Y = (w <= 1) ? Dg : Dga;
    size_t bse = (w <= 1) ? (size_t)12550144 : (size_t)12558336;
    int col = (w == 0 || w == 2) ? 0 : 1;
    int row = blockIdx.x, k = threadIdx.x;
    __shared__ float x[64], y[64];
    x[k] = X[(size_t)row * 64 + k];
    y[k] = Y[(size_t)row * 64 + k];
    __syncthreads();
    float wv = 0.f;
    #pragma unroll 8
    for (int j = 0; j < 64; j++) wv += BW[k * 64 + j] * y[j];
    float v = x[k] * wv;
    #pragma unroll
    for (int off = 32; off > 0; off >>= 1) v += __shfl_down(v, off);
    if (k == 0) {
        float r = v + bb[0];
        size_t ei = bse + (size_t)row * 2 + col;
        if (*flag) ((float*)outv)[ei] = r;
        else       ((u16*)outv)[ei] = f2bf(r);
    }
}

extern "C" void kernel_launch(void* const* d_in, const int* in_sizes, int n_in,
                              void* d_out, int out_size, void* d_ws, size_t ws_size,
                              hipStream_t stream) {
    const void* feat   = d_in[0];
    const void* feat_a = d_in[1];
    const void* adj    = d_in[2];
    const void* gn     = d_in[3];
    const void* w1     = d_in[4];
    const void* w2     = d_in[5];
    const void* attW   = d_in[6];
    const void* a_src  = d_in[7];
    const void* a_dst  = d_in[8];
    const void* mW1    = d_in[9];
    const void* mb1    = d_in[10];
    const void* mW2    = d_in[11];
    const void* mb2    = d_in[12];
    const void* mW3    = d_in[13];
    const void* mb3    = d_in[14];
    const void* dW1    = d_in[15];
    const void* db1    = d_in[16];
    const void* dW2    = d_in[17];
    const void* db2    = d_in[18];
    const void* bW     = d_in[19];
    const void* bb     = d_in[20];
    (void)in_sizes; (void)n_in; (void)out_size;

    // ---- d_ws: flag + T + W2tH/W2tL (~1.82 MB total) ----
    char* wsb = (char*)d_ws;
    int*   flag = (int*)wsb;                        // 4 B (pad 256)
    float* T    = (float*)(wsb + 256);              // 1,048,576 B
    u16*   W2tH = (u16*)(wsb + 256 + 1048576);      // 385,024 B
    u16*   W2tL = W2tH + 3008 * 64;                 // 385,024 B
    (void)ws_size;

    // ---- scratch arena at dtype-independent byte window of d_out:
    // bytes [1,048,576 , 21,200,000) lie inside the h output region for BOTH
    // bf16 (h bytes [524288,25100288)) and f32 (h bytes [1048576,50200576)),
    // and are fully overwritten by k_hgemm_mfma at the end.
    char* sc = (char*)d_out + 1048576;
    size_t soff = 0;
    auto salloc = [&](size_t nbytes) -> void* {
        void* p = (void*)(sc + soff);
        soff += (nbytes + 255) & ~(size_t)255;
        return p;
    };
    const size_t NV = (size_t)NN * 64;
    float* wA   = (float*)salloc((size_t)274689 * 4);  // 16-segment f32 weight arena
    int*   aCnt = (int*)salloc(NN * 4);
    int*   gCnt = (int*)salloc(NN * 4);
    int*   aIdx = (int*)salloc((size_t)NN * MAXN * 4);
    int*   gIdx = (int*)salloc((size_t)NN * MAXN * 4);
    float* X1  = (float*)salloc(NV * 4);
    float* X2  = (float*)salloc(NV * 4);   // contiguous with X1 (NV*4 is 256-mult)
    float* Wh1 = (float*)salloc(NV * 4);
    float* Wh2 = (float*)salloc(NV * 4);
    float* A1  = (float*)salloc(NV * 4);
    float* A2  = (float*)salloc(NV * 4);
    float* z   = (float*)salloc(NV * 4);
    float* za  = (float*)salloc(NV * 4);
    float* g   = (float*)salloc(NV * 4);
    float* ga  = (float*)salloc(NV * 4);
    float* De  = (float*)salloc(NV * 4);
    float* Dea = (float*)salloc(NV * 4);
    float* Dg  = (float*)salloc(NV * 4);
    float* Dga = (float*)salloc(NV * 4);
    float* s1  = (float*)salloc(NN * 4);
    float* s2  = (float*)salloc(NN * 4);
    float* d1  = (float*)salloc(NN * 4);
    float* d2  = (float*)salloc(NN * 4);
    // soff ~= 20.1 MB < 20.15 MB window: fits.

    float* w1f   = wA + 0;
    float* attWf = wA + 192000;
    float* asrcf = wA + 196096;
    float* adstf = wA + 196160;
    float* mW1f  = wA + 196224;
    float* mb1f  = wA + 212608;
    float* mW2f  = wA + 212864;
    float* mb2f  = wA + 245632;
    float* mW3f  = wA + 245760;
    float* mb3f  = wA + 253952;
    float* dW1f  = wA + 254016;
    float* db1f  = wA + 262208;
    float* dW2f  = wA + 262336;
    float* db2f  = wA + 270528;
    float* bWf   = wA + 270592;
    float* bbf   = wA + 274688;

    // BtH/BtL (split-bf16 W1^T [64][3008], 385 KB each) park in the De/Dea
    // slots: those are not written until k_dmlp, long after the feat GEMM.
    u16* BtH = (u16*)De;
    u16* BtL = (u16*)Dea;

    k_detect<<<1, 1024, 0, stream>>>((const u16*)feat, flag);
    k_convw<<<dim3(750, 16), 256, 0, stream>>>(flag,
        w1, attW, a_src, a_dst, mW1, mb1, mW2, mb2, mW3, mb3,
        dW1, db1, dW2, db2, bW, bb, wA);
    k_convw2t<<<752, 256, 0, stream>>>(flag, w2, W2tH, W2tL);
    k_convw1t<<<752, 256, 0, stream>>>(flag, w1, BtH, BtL);
    k_build_csr<<<dim3(NN, 2), 256, 0, stream>>>(flag, adj, gn, aCnt, aIdx, gCnt, gIdx);
    hipMemsetAsync(X1, 0, 2 * NV * 4, stream);   // zero X1+X2 for f32 K-split atomics
    k_featgemm_mfma<<<dim3(NN / 32, 2), 512, 0, stream>>>(flag, feat, feat_a, BtH, X1, X2);
    k_featgemm_mfma_f32<<<dim3(NN / 32, 2, 2), 512, 0, stream>>>(flag, feat, feat_a, BtH, BtL, X1, X2);
    k_whsd<<<dim3(NN, 2), 64, 0, stream>>>(X1, X2, attWf, asrcf, adstf, Wh1, Wh2, s1, s2, d1, d2);
    k_attn<<<dim3(NN, 2), 128, 0, stream>>>(aCnt, aIdx, s1, s2, d1, d2, Wh1, Wh2, A1, A2);
    k_mlp<<<dim3(NN / 4, 2), 256, 0, stream>>>(flag, A1, A2, mW1f, mb1f, mW2f, mb2f, mW3f, mb3f, z, za, d_out);
    k_readout<<<dim3(NN, 2), 64, 0, stream>>>(gCnt, gIdx, z, za, g, ga);
    k_dmlp<<<dim3(NN / 4, 4), 128, 0, stream>>>(z, za, g, ga, dW1f, db1f, dW2f, db2f, De, Dea, Dg, Dga);
    k_bilin<<<dim3(NN, 4), 64, 0, stream>>>(flag, De, Dea, Dg, Dga, bWf, bbf, d_out);
    k_spmm<<<NN, 64, 0, stream>>>(aCnt, aIdx, z, T);
    k_hgemm_mfma<<<dim3(NN / 32, 24), 256, 0, stream>>>(flag, T, W2tH, W2tL, d_out);
}

// Round 4
// 469.019 us; speedup vs baseline: 1.2532x; 1.0046x over previous
//
#include <hip/hip_runtime.h>

#define NN   4096
#define FIN  3000
#define MAXN 128

typedef unsigned short u16;
typedef __bf16 bf16x8 __attribute__((ext_vector_type(8)));
typedef float f32x16 __attribute__((ext_vector_type(16)));

__device__ __forceinline__ float bf2f(u16 u) { union { unsigned int i; float f; } v; v.i = ((unsigned int)u) << 16; return v.f; }
__device__ __forceinline__ u16 f2bf(float f) {
    union { float f; unsigned int i; } v; v.f = f;
    return (u16)((v.i + 0x7FFFu + ((v.i >> 16) & 1u)) >> 16);
}
__device__ __forceinline__ bf16x8 bzero8() {
    union { unsigned long long q[2]; bf16x8 v; } u; u.q[0] = 0ull; u.q[1] = 0ull; return u.v;
}
__device__ __forceinline__ f32x16 fzero16() {
    f32x16 v;
    #pragma unroll
    for (int i = 0; i < 16; i++) v[i] = 0.f;
    return v;
}

// ---- dtype detector: bf16 N(0,1) u16s have exponent ~127; f32-as-u16 halves are random.
__global__ __launch_bounds__(1024) void k_detect(const u16* __restrict__ feat, int* __restrict__ flag)
{
    __shared__ int tot;
    if (threadIdx.x == 0) tot = 0;
    __syncthreads();
    int ins = 0;
    for (int i = threadIdx.x; i < 16384; i += 1024) {
        u16 u = feat[i];
        int e = (u >> 7) & 0xFF;
        if (u != 0 && (e < 90 || e > 160)) ins++;
    }
    atomicAdd(&tot, ins);
    __syncthreads();
    if (threadIdx.x == 0) *flag = (tot > 1024) ? 1 : 0;   // 1 = inputs are f32
}

// ---- convert 16 weight tensors -> f32 arena (blockIdx.y = segment) ----
__global__ __launch_bounds__(256) void k_convw(const int* __restrict__ flag,
    const void* s0, const void* s1, const void* s2, const void* s3,
    const void* s4, const void* s5, const void* s6, const void* s7,
    const void* s8, const void* s9, const void* s10, const void* s11,
    const void* s12, const void* s13, const void* s14, const void* s15,
    float* __restrict__ dst)
{
    const void* srcs[16] = {s0,s1,s2,s3,s4,s5,s6,s7,s8,s9,s10,s11,s12,s13,s14,s15};
    const int offs[16] = {0,192000,196096,196160,196224,212608,212864,245632,245760,253952,254016,262208,262336,270528,270592,274688};
    const int ns[16]   = {192000,4096,64,64,16384,256,32768,128,8192,64,8192,128,8192,64,4096,1};
    int seg = blockIdx.y;
    int i = blockIdx.x * 256 + threadIdx.x;
    if (i >= ns[seg]) return;
    float v = (*flag) ? ((const float*)srcs[seg])[i] : bf2f(((const u16*)srcs[seg])[i]);
    dst[offs[seg] + i] = v;
}

// ---- build W2tH/W2tL = split-bf16 W2^T [3008][64] (n-major), zero-padded in n ----
__global__ __launch_bounds__(256) void k_convw2t(const int* __restrict__ flag,
    const void* __restrict__ src, u16* __restrict__ WH, u16* __restrict__ WL)
{
    int i = blockIdx.x * 256 + threadIdx.x;      // over 3008*64
    if (i >= 3008 * 64) return;
    int n = i >> 6, k = i & 63;
    float v = 0.f;
    if (n < FIN)
        v = (*flag) ? ((const float*)src)[(size_t)k * FIN + n]
                    : bf2f(((const u16*)src)[(size_t)k * FIN + n]);
    u16 h = f2bf(v);
    float r = v - bf2f(h);                       // exact in f32
    WH[i] = h;
    WL[i] = f2bf(r);
}

// ---- build BtH/BtL = split-bf16 W1^T [64][3008], zero-padded in k ----
// v = hi + lo + O(2^-18 * v): hi = bf16(v), lo = bf16(v - hi) (exact residual).
__global__ __launch_bounds__(256) void k_convw1t(const int* __restrict__ flag,
    const void* __restrict__ w1src, u16* __restrict__ BtH, u16* __restrict__ BtL)
{
    int i = blockIdx.x * 256 + threadIdx.x;      // over 64*3008
    if (i >= 64 * 3008) return;
    int c = i / 3008, k = i - c * 3008;
    float v = 0.f;
    if (k < 3000)
        v = (*flag) ? ((const float*)w1src)[(size_t)k * 64 + c]
                    : bf2f(((const u16*)w1src)[(size_t)k * 64 + c]);
    u16 h = f2bf(v);
    float r = v - bf2f(h);                       // exact in f32
    BtH[(size_t)c * 3008 + k] = h;
    BtL[(size_t)c * 3008 + k] = f2bf(r);
}

// ---- ordered CSR build (prefix-scan, deterministic, sorted) for adj / graph_neigh ----
// vectorized loads: f32 path 4x float4, u16 path 2x uint4 per thread (64B / 32B).
__global__ __launch_bounds__(256) void k_build_csr(const int* __restrict__ flag,
    const void* __restrict__ Av, const void* __restrict__ Gv,
    int* __restrict__ aCnt, int* __restrict__ aIdx,
    int* __restrict__ gCnt, int* __restrict__ gIdx)
{
    bool isf = (*flag != 0);
    const void* M = blockIdx.y ? Gv : Av;
    int* cnt = blockIdx.y ? gCnt : aCnt;
    int* idx = blockIdx.y ? gIdx : aIdx;
    int row = blockIdx.x, t = threadIdx.x;
    int c0 = t * 16;
    unsigned int mask = 0; int my = 0;
    if (isf) {
        const float4* r = (const float4*)((const float*)M + (size_t)row * NN + c0);
        union { float4 q[4]; float f[16]; } u;
        u.q[0] = r[0]; u.q[1] = r[1]; u.q[2] = r[2]; u.q[3] = r[3];
        #pragma unroll
        for (int j = 0; j < 16; j++) if (u.f[j] != 0.f) { mask |= 1u << j; my++; }
    } else {
        const uint4* r = (const uint4*)((const u16*)M + (size_t)row * NN + c0);
        union { uint4 q[2]; u16 h[16]; } u;
        u.q[0] = r[0]; u.q[1] = r[1];
        #pragma unroll
        for (int j = 0; j < 16; j++) if (u.h[j] != 0) { mask |= 1u << j; my++; }
    }
    __shared__ int sc[256];
    sc[t] = my;
    __syncthreads();
    for (int d = 1; d < 256; d <<= 1) {
        int v = (t >= d) ? sc[t - d] : 0;
        __syncthreads();
        sc[t] += v;
        __syncthreads();
    }
    int pos = sc[t] - my;
    for (int j = 0; j < 16; j++) {
        if (mask & (1u << j)) {
            if (pos < MAXN) idx[(size_t)row * MAXN + pos] = c0 + j;
            pos++;
        }
    }
    if (t == 0) { int total = sc[255]; cnt[row] = (total < MAXN) ? total : MAXN; }
}

// ---- bf16-input path: X = feat @ weight1 via 1-term v_mfma_f32_32x32x16_bf16 ----
__global__ __launch_bounds__(512) void k_featgemm_mfma(const int* __restrict__ flag,
    const void* __restrict__ F0v, const void* __restrict__ F1v,
    const u16* __restrict__ BtH, float* __restrict__ X0, float* __restrict__ X1)
{
    if (*flag) return;                     // f32 mode: handled by k_featgemm_mfma_f32
    const u16* F = (const u16*)(blockIdx.y ? F1v : F0v);
    float* X = blockIdx.y ? X1 : X0;
    int r0 = blockIdx.x * 32;
    int tid = threadIdx.x;
    int w  = tid >> 6;                     // wave id = K-eighth
    int l  = tid & 63;
    int lr = l & 31;                       // A row / B col / D col
    int kg = l >> 5;                       // k-group (0..1), 8 elems each
    const u16* arow = F   + (size_t)(r0 + lr) * FIN + kg * 8;
    const u16* b0p  = BtH + (size_t)lr * 3008 + kg * 8;
    const u16* b1p  = BtH + (size_t)(lr + 32) * 3008 + kg * 8;
    f32x16 acc0 = fzero16(), acc1 = fzero16();
    #pragma unroll 4
    for (int s = w; s < 188; s += 8) {
        int kk = s * 16;
        bf16x8 a;
        if (kk + kg * 8 < FIN) a = *(const bf16x8*)(arow + kk);
        else                   a = bzero8();
        bf16x8 b0 = *(const bf16x8*)(b0p + kk);   // Bt zero-padded to 3008
        bf16x8 b1 = *(const bf16x8*)(b1p + kk);
        acc0 = __builtin_amdgcn_mfma_f32_32x32x16_bf16(a, b0, acc0, 0, 0, 0);
        acc1 = __builtin_amdgcn_mfma_f32_32x32x16_bf16(a, b1, acc1, 0, 0, 0);
    }
    __shared__ float red[8][2048];         // 64 KB: per-wave 32x64 partials
    float* rp = red[w];
    #pragma unroll
    for (int reg = 0; reg < 16; reg++) {
        int row = (reg & 3) + 8 * (reg >> 2) + 4 * kg;
        rp[row * 64 + lr] = acc0[reg];
    }
    #pragma unroll
    for (int reg = 0; reg < 16; reg++) {
        int row = (reg & 3) + 8 * (reg >> 2) + 4 * kg;
        rp[row * 64 + 32 + lr] = acc1[reg];
    }
    __syncthreads();
    for (int i = tid; i < 2048; i += 512) {
        float s0 = 0.f;
        #pragma unroll
        for (int j = 0; j < 8; j++) s0 += red[j][i];
        X[(size_t)r0 * 64 + i] = s0;
    }
}

// ---- pipelined helpers for the f32 featgemm ----
__device__ __forceinline__ void fg_issue(
    const float* __restrict__ arow,
    const u16* __restrict__ b0h, const u16* __restrict__ b1h,
    const u16* __restrict__ b0l, const u16* __restrict__ b1l,
    int s, int kg,
    float4& A0, float4& A1, bf16x8& H0, bf16x8& H1, bf16x8& L0, bf16x8& L1)
{
    if (s < 188) {
        int kk = s * 16;
        if (kk + kg * 8 < FIN) {
            A0 = *(const float4*)(arow + kk);
            A1 = *(const float4*)(arow + kk + 4);
        } else {
            A0 = make_float4(0.f, 0.f, 0.f, 0.f);
            A1 = make_float4(0.f, 0.f, 0.f, 0.f);
        }
        H0 = *(const bf16x8*)(b0h + kk);
        H1 = *(const bf16x8*)(b1h + kk);
        L0 = *(const bf16x8*)(b0l + kk);
        L1 = *(const bf16x8*)(b1l + kk);
    } else {
        A0 = make_float4(0.f, 0.f, 0.f, 0.f);
        A1 = make_float4(0.f, 0.f, 0.f, 0.f);
        H0 = bzero8(); H1 = bzero8(); L0 = bzero8(); L1 = bzero8();
    }
}

__device__ __forceinline__ void fg_step(
    const float4& A0, const float4& A1,
    const bf16x8& H0, const bf16x8& H1, const bf16x8& L0, const bf16x8& L1,
    f32x16& acc0, f32x16& acc1)
{
    float av[8] = {A0.x, A0.y, A0.z, A0.w, A1.x, A1.y, A1.z, A1.w};
    bf16x8 ah, al;
    #pragma unroll
    for (int j = 0; j < 8; j++) {
        __bf16 hv = (__bf16)av[j];
        ah[j] = hv;
        al[j] = (__bf16)(av[j] - (float)hv);     // exact residual
    }
    acc0 = __builtin_amdgcn_mfma_f32_32x32x16_bf16(ah, H0, acc0, 0, 0, 0);
    acc0 = __builtin_amdgcn_mfma_f32_32x32x16_bf16(al, H0, acc0, 0, 0, 0);
    acc0 = __builtin_amdgcn_mfma_f32_32x32x16_bf16(ah, L0, acc0, 0, 0, 0);
    acc1 = __builtin_amdgcn_mfma_f32_32x32x16_bf16(ah, H1, acc1, 0, 0, 0);
    acc1 = __builtin_amdgcn_mfma_f32_32x32x16_bf16(al, H1, acc1, 0, 0, 0);
    acc1 = __builtin_amdgcn_mfma_f32_32x32x16_bf16(ah, L1, acc1, 0, 0, 0);
}

// ---- f32-input path: X = feat @ weight1 via split-bf16 3-term MFMA ----
// Depth-2 software pipeline: while step si computes, step si+1's 6 loads are in
// flight and si+2's are issued right after -> ~6 outstanding loads/wave instead
// of ~1 (the round-3 concurrency bottleneck: 884 GB/s, all pipes <7% busy).
// 2-way K-split across blockIdx.z; atomicAdd epilogue into memset X.
__global__ __launch_bounds__(512) void k_featgemm_mfma_f32(const int* __restrict__ flag,
    const void* __restrict__ F0v, const void* __restrict__ F1v,
    const u16* __restrict__ BtH, const u16* __restrict__ BtL,
    float* __restrict__ X0, float* __restrict__ X1)
{
    if (!*flag) return;                    // bf16 mode: handled by k_featgemm_mfma
    const float* F = (const float*)(blockIdx.y ? F1v : F0v);
    float* X = blockIdx.y ? X1 : X0;
    int r0 = blockIdx.x * 32;
    int tid = threadIdx.x;
    int w  = tid >> 6;                     // wave id
    int l  = tid & 63;
    int lr = l & 31;                       // A row / B col / D col
    int kg = l >> 5;                       // k-group (0..1), 8 elems each
    int s0 = blockIdx.z * 8 + w;           // K-slot 0..15, step 16
    const float* arow = F + (size_t)(r0 + lr) * FIN + kg * 8;
    const u16* b0h = BtH + (size_t)lr * 3008 + kg * 8;
    const u16* b1h = BtH + (size_t)(lr + 32) * 3008 + kg * 8;
    const u16* b0l = BtL + (size_t)lr * 3008 + kg * 8;
    const u16* b1l = BtL + (size_t)(lr + 32) * 3008 + kg * 8;

    float4 A0[2], A1[2];
    bf16x8 H0[2], H1[2], L0[2], L1[2];
    fg_issue(arow, b0h, b1h, b0l, b1l, s0,      kg, A0[0], A1[0], H0[0], H1[0], L0[0], L1[0]);
    fg_issue(arow, b0h, b1h, b0l, b1l, s0 + 16, kg, A0[1], A1[1], H0[1], H1[1], L0[1], L1[1]);
    f32x16 acc0 = fzero16(), acc1 = fzero16();
    #pragma unroll
    for (int si = 0; si < 12; si++) {      // full unroll: slot index compile-time
        int sl = si & 1;
        fg_step(A0[sl], A1[sl], H0[sl], H1[sl], L0[sl], L1[sl], acc0, acc1);
        if (si + 2 < 12)
            fg_issue(arow, b0h, b1h, b0l, b1l, s0 + (si + 2) * 16, kg,
                     A0[sl], A1[sl], H0[sl], H1[sl], L0[sl], L1[sl]);
    }

    __shared__ float red[8][2048];         // 64 KB: per-wave 32x64 partials
    float* rp = red[w];
    #pragma unroll
    for (int reg = 0; reg < 16; reg++) {
        int row = (reg & 3) + 8 * (reg >> 2) + 4 * kg;
        rp[row * 64 + lr] = acc0[reg];
    }
    #pragma unroll
    for (int reg = 0; reg < 16; reg++) {
        int row = (reg & 3) + 8 * (reg >> 2) + 4 * kg;
        rp[row * 64 + 32 + lr] = acc1[reg];
    }
    __syncthreads();
    for (int i = tid; i < 2048; i += 512) {
        float s0s = 0.f;
        #pragma unroll
        for (int j = 0; j < 8; j++) s0s += red[j][i];
        atomicAdd(&X[(size_t)r0 * 64 + i], s0s);
    }
}

// ---- Wh = X @ att_W; s = Wh@a_src; d = Wh@a_dst (all-f32) ----
__global__ __launch_bounds__(64) void k_whsd(
    const float* __restrict__ X1, const float* __restrict__ X2,
    const float* __restrict__ AW, const float* __restrict__ asrc, const float* __restrict__ adst,
    float* __restrict__ Wh1, float* __restrict__ Wh2,
    float* __restrict__ s1, float* __restrict__ s2,
    float* __restrict__ d1, float* __restrict__ d2)
{
    const float* X = blockIdx.y ? X2 : X1;
    float* Wh = blockIdx.y ? Wh2 : Wh1;
    float* sv = blockIdx.y ? s2 : s1;
    float* dv = blockIdx.y ? d2 : d1;
    int row = blockIdx.x, c = threadIdx.x;
    __shared__ float x[64];
    x[c] = X[(size_t)row * 64 + c];
    __syncthreads();
    float acc = 0.f;
    #pragma unroll 16
    for (int k = 0; k < 64; k++) acc += x[k] * AW[k * 64 + c];
    Wh[(size_t)row * 64 + c] = acc;
    float vs = acc * asrc[c];
    float vd = acc * adst[c];
    #pragma unroll
    for (int off = 32; off > 0; off >>= 1) { vs += __shfl_down(vs, off); vd += __shfl_down(vd, off); }
    if (c == 0) { sv[row] = vs; dv[row] = vd; }
}

// ---- masked softmax (rank-1 scores) + P @ Wh over CSR neighbors ----
__global__ __launch_bounds__(128) void k_attn(
    const int* __restrict__ cnt, const int* __restrict__ idx,
    const float* __restrict__ s1, const float* __restrict__ s2,
    const float* __restrict__ d1, const float* __restrict__ d2,
    const float* __restrict__ Wh1, const float* __restrict__ Wh2,
    float* __restrict__ A1, float* __restrict__ A2)
{
    const float* sp = blockIdx.y ? s2 : s1;
    const float* dp = blockIdx.y ? d2 : d1;
    const float* Wh = blockIdx.y ? Wh2 : Wh1;
    float* A = blockIdx.y ? A2 : A1;
    int row = blockIdx.x, tid = threadIdx.x;
    int n = cnt[row];
    __shared__ int js[MAXN];
    __shared__ float ps[MAXN];
    __shared__ float red2[2];
    __shared__ float ared[2][64];
    for (int k = tid; k < n; k += 128) js[k] = idx[(size_t)row * MAXN + k];
    __syncthreads();
    float si = sp[row];
    float m = -3.0e38f;
    for (int k = tid; k < n; k += 128) {
        float e = si + dp[js[k]];
        e = e > 0.f ? e : 0.2f * e;   // LeakyReLU(0.2)
        ps[k] = e;
        m = fmaxf(m, e);
    }
    #pragma unroll
    for (int off = 32; off > 0; off >>= 1) m = fmaxf(m, __shfl_down(m, off));
    if ((tid & 63) == 0) red2[tid >> 6] = m;
    __syncthreads();
    m = fmaxf(red2[0], red2[1]);
    __syncthreads();
    float zz = 0.f;
    for (int k = tid; k < n; k += 128) {
        float p = __expf(ps[k] - m);
        ps[k] = p;
        zz += p;
    }
    #pragma unroll
    for (int off = 32; off > 0; off >>= 1) zz += __shfl_down(zz, off);
    if ((tid & 63) == 0) red2[tid >> 6] = zz;
    __syncthreads();
    float Z = red2[0] + red2[1];
    Z = fmaxf(Z, 1e-20f);           // guard 0/0
    int f = tid & 63, half = tid >> 6;
    float acc = 0.f;
    for (int k = half; k < n; k += 2) acc += ps[k] * Wh[(size_t)js[k] * 64 + f];
    ared[half][f] = acc;
    __syncthreads();
    if (tid < 64) A[(size_t)row * 64 + f] = (ared[0][f] + ared[1][f]) / Z;
}

// ---- 3-layer MLP 64->256->128->64; 4 rows/block; writes z (f32) and hiden_emb (dual-dtype, y==0) ----
__global__ __launch_bounds__(256) void k_mlp(const int* __restrict__ flag,
    const float* __restrict__ A1, const float* __restrict__ A2,
    const float* __restrict__ W1, const float* __restrict__ b1,
    const float* __restrict__ W2, const float* __restrict__ b2,
    const float* __restrict__ W3, const float* __restrict__ b3,
    float* __restrict__ Z1, float* __restrict__ Z2, void* __restrict__ hidenv)
{
    const float* A = blockIdx.y ? A2 : A1;
    float* Z = blockIdx.y ? Z2 : Z1;
    int row0 = blockIdx.x * 4, tid = threadIdx.x;
    __shared__ float x[4][64], h1[4][256], h2[4][128];
    {
        int r = tid >> 6, c = tid & 63;
        x[r][c] = A[(size_t)(row0 + r) * 64 + c];
    }
    __syncthreads();
    {
        float a0 = b1[tid], a1v = a0, a2v = a0, a3v = a0;
        #pragma unroll 8
        for (int k = 0; k < 64; k++) {
            float w = W1[k * 256 + tid];
            a0 += x[0][k] * w; a1v += x[1][k] * w; a2v += x[2][k] * w; a3v += x[3][k] * w;
        }
        h1[0][tid] = fmaxf(a0, 0.f);  h1[1][tid] = fmaxf(a1v, 0.f);
        h1[2][tid] = fmaxf(a2v, 0.f); h1[3][tid] = fmaxf(a3v, 0.f);
    }
    __syncthreads();
    if (tid < 128) {
        float a0 = b2[tid], a1v = a0, a2v = a0, a3v = a0;
        #pragma unroll 8
        for (int k = 0; k < 256; k++) {
            float w = W2[k * 128 + tid];
            a0 += h1[0][k] * w; a1v += h1[1][k] * w; a2v += h1[2][k] * w; a3v += h1[3][k] * w;
        }
        h2[0][tid] = fmaxf(a0, 0.f);  h2[1][tid] = fmaxf(a1v, 0.f);
        h2[2][tid] = fmaxf(a2v, 0.f); h2[3][tid] = fmaxf(a3v, 0.f);
    }
    __syncthreads();
    if (tid < 64) {
        float a[4];
        a[0] = a[1] = a[2] = a[3] = b3[tid];
        #pragma unroll 8
        for (int k = 0; k < 128; k++) {
            float w = W3[k * 64 + tid];
            a[0] += h2[0][k] * w; a[1] += h2[1][k] * w; a[2] += h2[2][k] * w; a[3] += h2[3][k] * w;
        }
        bool isf = (*flag != 0);
        #pragma unroll
        for (int r = 0; r < 4; r++) {
            size_t ei = (size_t)(row0 + r) * 64 + tid;
            Z[ei] = a[r];
            if (blockIdx.y == 0) {
                if (isf) ((float*)hidenv)[ei] = a[r];
                else     ((u16*)hidenv)[ei] = f2bf(a[r]);
            }
        }
    }
}

// ---- T = adj @ z over CSR ----
__global__ __launch_bounds__(64) void k_spmm(
    const int* __restrict__ cnt, const int* __restrict__ idx,
    const float* __restrict__ Z, float* __restrict__ T)
{
    int row = blockIdx.x, f = threadIdx.x;
    int n = cnt[row];
    const int* ir = idx + (size_t)row * MAXN;
    float acc = 0.f;
    for (int k = 0; k < n; k++) acc += Z[(size_t)ir[k] * 64 + f];
    T[(size_t)row * 64 + f] = acc;
}

// ---- H = T @ weight2 via split-bf16 3-term MFMA -> out (dual-dtype store) ----
__global__ __launch_bounds__(256) void k_hgemm_mfma(const int* __restrict__ flag,
    const float* __restrict__ T, const u16* __restrict__ WH, const u16* __restrict__ WL,
    void* __restrict__ outv)
{
    bool isf = (*flag != 0);
    int tid = threadIdx.x;
    int w = tid >> 6, l = tid & 63, lr = l & 31, kg = l >> 5;
    int ct = blockIdx.y * 4 + w;
    if (ct >= 94) return;                  // wave-uniform; no barriers in kernel
    int r0 = blockIdx.x * 32, c0 = ct * 32;
    const float* tp = T + (size_t)(r0 + lr) * 64 + kg * 8;
    bf16x8 ah[4], al[4];
    #pragma unroll
    for (int s = 0; s < 4; s++) {
        float4 p0 = *(const float4*)(tp + s * 16);
        float4 p1 = *(const float4*)(tp + s * 16 + 4);
        float av[8] = {p0.x, p0.y, p0.z, p0.w, p1.x, p1.y, p1.z, p1.w};
        #pragma unroll
        for (int j = 0; j < 8; j++) {
            __bf16 hv = (__bf16)av[j];
            ah[s][j] = hv;
            al[s][j] = (__bf16)(av[j] - (float)hv);   // exact residual
        }
    }
    const u16* bh = WH + (size_t)(c0 + lr) * 64 + kg * 8;
    const u16* bl = WL + (size_t)(c0 + lr) * 64 + kg * 8;
    f32x16 acc = fzero16();
    #pragma unroll
    for (int s = 0; s < 4; s++) {
        bf16x8 vh = *(const bf16x8*)(bh + s * 16);
        bf16x8 vl = *(const bf16x8*)(bl + s * 16);
        acc = __builtin_amdgcn_mfma_f32_32x32x16_bf16(ah[s], vh, acc, 0, 0, 0);
        acc = __builtin_amdgcn_mfma_f32_32x32x16_bf16(al[s], vh, acc, 0, 0, 0);
        acc = __builtin_amdgcn_mfma_f32_32x32x16_bf16(ah[s], vl, acc, 0, 0, 0);
    }
    int col = c0 + lr;
    bool cok = col < FIN;
    #pragma unroll
    for (int reg = 0; reg < 16; reg++) {
        int row = (reg & 3) + 8 * (reg >> 2) + 4 * kg;
        size_t ei = 262144 + (size_t)(r0 + row) * FIN + col;
        if (cok) {
            if (isf) ((float*)outv)[ei] = acc[reg];
            else     ((u16*)outv)[ei] = f2bf(acc[reg]);
        }
    }
}

// ---- readout: mean over graph_neigh nbrs of relu(z), L2 normalize, sigmoid ----
__global__ __launch_bounds__(64) void k_readout(
    const int* __restrict__ cnt, const int* __restrict__ idx,
    const float* __restrict__ Z1, const float* __restrict__ Z2,
    float* __restrict__ G1, float* __restrict__ G2)
{
    const float* Z = blockIdx.y ? Z2 : Z1;
    float* G = blockIdx.y ? G2 : G1;
    int row = blockIdx.x, f = threadIdx.x;
    int n = cnt[row];
    const int* ir = idx + (size_t)row * MAXN;
    float acc = 0.f;
    for (int k = 0; k < n; k++) acc += fmaxf(Z[(size_t)ir[k] * 64 + f], 0.f);
    acc /= (float)(n > 0 ? n : 1);
    float sq = acc * acc;
    #pragma unroll
    for (int off = 32; off > 0; off >>= 1) sq += __shfl_down(sq, off);
    sq = __shfl(sq, 0);
    float nrm = fmaxf(sqrtf(sq), 1e-12f);
    float v = acc / nrm;
    G[(size_t)row * 64 + f] = 1.f / (1.f + __expf(-v));
}

// ---- discriminator MLP 64->128->64; 4 rows/block; on {relu(z), relu(z_a), g, g_a} ----
__global__ __launch_bounds__(128) void k_dmlp(
    const float* __restrict__ z, const float* __restrict__ za,
    const float* __restrict__ g, const float* __restrict__ ga,
    const float* __restrict__ W1, const float* __restrict__ b1,
    const float* __restrict__ W2, const float* __restrict__ b2,
    float* __restrict__ De, float* __restrict__ Dea,
    float* __restrict__ Dg, float* __restrict__ Dga)
{
    int w = blockIdx.y;
    const float* X = (w == 0) ? z : (w == 1) ? za : (w == 2) ? g : ga;
    float* O = (w == 0) ? De : (w == 1) ? Dea : (w == 2) ? Dg : Dga;
    int doRelu = (w < 2);
    int row0 = blockIdx.x * 4, tid = threadIdx.x;
    __shared__ float x[4][64], h1[4][128];
    for (int i = tid; i < 256; i += 128) {
        int r = i >> 6, c = i & 63;
        float v = X[(size_t)(row0 + r) * 64 + c];
        x[r][c] = doRelu ? fmaxf(v, 0.f) : v;
    }
    __syncthreads();
    {
        float a0 = b1[tid], a1v = a0, a2v = a0, a3v = a0;
        #pragma unroll 8
        for (int k = 0; k < 64; k++) {
            float w_ = W1[k * 128 + tid];
            a0 += x[0][k] * w_; a1v += x[1][k] * w_; a2v += x[2][k] * w_; a3v += x[3][k] * w_;
        }
        h1[0][tid] = fmaxf(a0, 0.f);  h1[1][tid] = fmaxf(a1v, 0.f);
        h1[2][tid] = fmaxf(a2v, 0.f); h1[3][tid] = fmaxf(a3v, 0.f);
    }
    __syncthreads();
    if (tid < 64) {
        float a[4];
        a[0] = a[1] = a[2] = a[3] = b2[tid];
        #pragma unroll 8
        for (int k = 0; k < 128; k++) {
            float w_ = W2[k * 64 + tid];
            a[0] += h1[0][k] * w_; a[1] += h1[1][k] * w_; a[2] += h1[2][k] * w_; a[3] += h1[3][k] * w_;
        }
        #pragma unroll
        for (int r = 0; r < 4; r++) O[(size_t)(row0 + r) * 64 + tid] = a[r];
    }
}

// ---- bilinear: out = x . (bil_W @ y) + b ; dual-dtype store ----
__global__ __launch_bounds__(64) void k_bilin(const int* __restrict__ flag,
    const float* __restrict__ De, const float* __restrict__ Dea,
    const float* __restrict__ Dg, const float* __restrict__ Dga,
    const float* __restrict__ BW, const float* __restrict__ bb, void* __restrict__ outv)
{
    int w = blockIdx.y;
    const float* X = (w == 0 || w == 3) ? De : Dea;
    const float* Y = (w <= 1) ? Dg : Dga;
    size_t bse = (w <= 1) ? (size_t)12550144 : (size_t)12558336;
    int col = (w == 0 || w == 2) ? 0 : 1;
    int row = blockIdx.x, k = threadIdx.x;
    __shared__ float x[64], y[64];
    x[k] = X[(size_t)row * 64 + k];
    y[k] = Y[(size_t)row * 64 + k];
    __syncthreads();
    float wv = 0.f;
    #pragma unroll 8
    for (int j = 0; j < 64; j++) wv += BW[k * 64 + j] * y[j];
    float v = x[k] * wv;
    #pragma unroll
    for (int off = 32; off > 0; off >>= 1) v += __shfl_down(v, off);
    if (k == 0) {
        float r = v + bb[0];
        size_t ei = bse + (size_t)row * 2 + col;
        if (*flag) ((float*)outv)[ei] = r;
        else       ((u16*)outv)[ei] = f2bf(r);
    }
}

extern "C" void kernel_launch(void* const* d_in, const int* in_sizes, int n_in,
                              void* d_out, int out_size, void* d_ws, size_t ws_size,
                              hipStream_t stream) {
    const void* feat   = d_in[0];
    const void* feat_a = d_in[1];
    const void* adj    = d_in[2];
    const void* gn     = d_in[3];
    const void* w1     = d_in[4];
    const void* w2     = d_in[5];
    const void* attW   = d_in[6];
    const void* a_src  = d_in[7];
    const void* a_dst  = d_in[8];
    const void* mW1    = d_in[9];
    const void* mb1    = d_in[10];
    const void* mW2    = d_in[11];
    const void* mb2    = d_in[12];
    const void* mW3    = d_in[13];
    const void* mb3    = d_in[14];
    const void* dW1    = d_in[15];
    const void* db1    = d_in[16];
    const void* dW2    = d_in[17];
    const void* db2    = d_in[18];
    const void* bW     = d_in[19];
    const void* bb     = d_in[20];
    (void)in_sizes; (void)n_in; (void)out_size;

    // ---- d_ws: flag + T + W2tH/W2tL (~1.82 MB total) ----
    char* wsb = (char*)d_ws;
    int*   flag = (int*)wsb;                        // 4 B (pad 256)
    float* T    = (float*)(wsb + 256);              // 1,048,576 B
    u16*   W2tH = (u16*)(wsb + 256 + 1048576);      // 385,024 B
    u16*   W2tL = W2tH + 3008 * 64;                 // 385,024 B
    (void)ws_size;

    // ---- scratch arena at dtype-independent byte window of d_out:
    // bytes [1,048,576 , 21,200,000) lie inside the h output region for BOTH
    // bf16 (h bytes [524288,25100288)) and f32 (h bytes [1048576,50200576)),
    // and are fully overwritten by k_hgemm_mfma at the end.
    char* sc = (char*)d_out + 1048576;
    size_t soff = 0;
    auto salloc = [&](size_t nbytes) -> void* {
        void* p = (void*)(sc + soff);
        soff += (nbytes + 255) & ~(size_t)255;
        return p;
    };
    const size_t NV = (size_t)NN * 64;
    float* wA   = (float*)salloc((size_t)274689 * 4);  // 16-segment f32 weight arena
    int*   aCnt = (int*)salloc(NN * 4);
    int*   gCnt = (int*)salloc(NN * 4);
    int*   aIdx = (int*)salloc((size_t)NN * MAXN * 4);
    int*   gIdx = (int*)salloc((size_t)NN * MAXN * 4);
    float* X1  = (float*)salloc(NV * 4);
    float* X2  = (float*)salloc(NV * 4);   // contiguous with X1 (NV*4 is 256-mult)
    float* Wh1 = (float*)salloc(NV * 4);
    float* Wh2 = (float*)salloc(NV * 4);
    float* A1  = (float*)salloc(NV * 4);
    float* A2  = (float*)salloc(NV * 4);
    float* z   = (float*)salloc(NV * 4);
    float* za  = (float*)salloc(NV * 4);
    float* g   = (float*)salloc(NV * 4);
    float* ga  = (float*)salloc(NV * 4);
    float* De  = (float*)salloc(NV * 4);
    float* Dea = (float*)salloc(NV * 4);
    float* Dg  = (float*)salloc(NV * 4);
    float* Dga = (float*)salloc(NV * 4);
    float* s1  = (float*)salloc(NN * 4);
    float* s2  = (float*)salloc(NN * 4);
    float* d1  = (float*)salloc(NN * 4);
    float* d2  = (float*)salloc(NN * 4);
    // soff ~= 20.1 MB < 20.15 MB window: fits.

    float* w1f   = wA + 0;
    float* attWf = wA + 192000;
    float* asrcf = wA + 196096;
    float* adstf = wA + 196160;
    float* mW1f  = wA + 196224;
    float* mb1f  = wA + 212608;
    float* mW2f  = wA + 212864;
    float* mb2f  = wA + 245632;
    float* mW3f  = wA + 245760;
    float* mb3f  = wA + 253952;
    float* dW1f  = wA + 254016;
    float* db1f  = wA + 262208;
    float* dW2f  = wA + 262336;
    float* db2f  = wA + 270528;
    float* bWf   = wA + 270592;
    float* bbf   = wA + 274688;

    // BtH/BtL (split-bf16 W1^T [64][3008], 385 KB each) park in the De/Dea
    // slots: those are not written until k_dmlp, long after the feat GEMM.
    u16* BtH = (u16*)De;
    u16* BtL = (u16*)Dea;

    k_detect<<<1, 1024, 0, stream>>>((const u16*)feat, flag);
    k_convw<<<dim3(750, 16), 256, 0, stream>>>(flag,
        w1, attW, a_src, a_dst, mW1, mb1, mW2, mb2, mW3, mb3,
        dW1, db1, dW2, db2, bW, bb, wA);
    k_convw2t<<<752, 256, 0, stream>>>(flag, w2, W2tH, W2tL);
    k_convw1t<<<752, 256, 0, stream>>>(flag, w1, BtH, BtL);
    k_build_csr<<<dim3(NN, 2), 256, 0, stream>>>(flag, adj, gn, aCnt, aIdx, gCnt, gIdx);
    hipMemsetAsync(X1, 0, 2 * NV * 4, stream);   // zero X1+X2 for f32 K-split atomics
    k_featgemm_mfma<<<dim3(NN / 32, 2), 512, 0, stream>>>(flag, feat, feat_a, BtH, X1, X2);
    k_featgemm_mfma_f32<<<dim3(NN / 32, 2, 2), 512, 0, stream>>>(flag, feat, feat_a, BtH, BtL, X1, X2);
    k_whsd<<<dim3(NN, 2), 64, 0, stream>>>(X1, X2, attWf, asrcf, adstf, Wh1, Wh2, s1, s2, d1, d2);
    k_attn<<<dim3(NN, 2), 128, 0, stream>>>(aCnt, aIdx, s1, s2, d1, d2, Wh1, Wh2, A1, A2);
    k_mlp<<<dim3(NN / 4, 2), 256, 0, stream>>>(flag, A1, A2, mW1f, mb1f, mW2f, mb2f, mW3f, mb3f, z, za, d_out);
    k_readout<<<dim3(NN, 2), 64, 0, stream>>>(gCnt, gIdx, z, za, g, ga);
    k_dmlp<<<dim3(NN / 4, 4), 128, 0, stream>>>(z, za, g, ga, dW1f, db1f, dW2f, db2f, De, Dea, Dg, Dga);
    k_bilin<<<dim3(NN, 4), 64, 0, stream>>>(flag, De, Dea, Dg, Dga, bWf, bbf, d_out);
    k_spmm<<<NN, 64, 0, stream>>>(aCnt, aIdx, z, T);
    k_hgemm_mfma<<<dim3(NN / 32, 24), 256, 0, stream>>>(flag, T, W2tH, W2tL, d_out);
}